// Round 2
// baseline (652.646 us; speedup 1.0000x reference)
//
#include <hip/hip_runtime.h>

// ProxemicsFieldGenerator: 2-layer GAT on dense graph.
// b=16, n=1024, f0=32, h0=4, f1=16, F1H=64, f2=32, h1=1.

namespace {
constexpr int Nn  = 1024;
constexpr int F0  = 32;
constexpr int H0n = 4;
constexpr int F1n = 16;
constexpr int FH  = 64;   // H0n * F1n
constexpr int F2n = 32;
constexpr float LOG2E = 1.4426950408889634f;
constexpr float EPS   = 1e-5f;
constexpr float ALPHA = 0.2f;
}

// ---------------------------------------------------------------------------
// K1: instance-norm(x) -> h_prime1 [b,h,n,16], src1/dst1 [b,h,n]
// grid = 16 b * 4 ntiles, block = 256
// ---------------------------------------------------------------------------
__global__ __launch_bounds__(256) void k_norm_proj1(
    const float* __restrict__ x, const float* __restrict__ w1,
    const float* __restrict__ asrc, const float* __restrict__ adst,
    float* __restrict__ hp, float* __restrict__ src, float* __restrict__ dst)
{
  const int b     = blockIdx.x >> 2;
  const int ntile = blockIdx.x & 3;
  const int tid   = threadIdx.x;

  __shared__ float s_sum[8][32];
  __shared__ float s_ssq[8][32];
  __shared__ float s_mean[32];
  __shared__ float s_rstd[32];
  __shared__ float s_wt[H0n * F1n * F0];   // transposed: [h][o][f]
  __shared__ float s_as[H0n * F1n];
  __shared__ float s_ad[H0n * F1n];

  for (int idx = tid; idx < H0n * F1n * F0; idx += 256) {
    const int f  = idx & 31;
    const int ho = idx >> 5;               // h*16 + o
    const int h  = ho >> 4, o = ho & 15;
    s_wt[idx] = w1[(h * F0 + f) * F1n + o];
  }
  if (tid < H0n * F1n) { s_as[tid] = asrc[tid]; s_ad[tid] = adst[tid]; }

  // --- stats over n for each of 32 channels (redundant per ntile, cheap) ---
  const float* xb = x + (size_t)b * Nn * F0;
  const int c = tid & 31, sub = tid >> 5;
  float sum = 0.f, ssq = 0.f;
  for (int nn = sub; nn < Nn; nn += 8) {
    float v = xb[nn * F0 + c];
    sum += v; ssq += v * v;
  }
  s_sum[sub][c] = sum; s_ssq[sub][c] = ssq;
  __syncthreads();
  if (tid < 32) {
    float s = 0.f, q = 0.f;
#pragma unroll
    for (int k = 0; k < 8; k++) { s += s_sum[k][tid]; q += s_ssq[k][tid]; }
    const float mean = s * (1.f / Nn);
    const float var  = fmaf(-mean, mean, q * (1.f / Nn));
    s_mean[tid] = mean;
    s_rstd[tid] = rsqrtf(var + EPS);
  }
  __syncthreads();

  // --- one row per thread: normalize + project ---
  const int n = ntile * 256 + tid;
  float4 xn[F0 / 4];
  const float4* xrow = reinterpret_cast<const float4*>(xb + (size_t)n * F0);
#pragma unroll
  for (int f4 = 0; f4 < F0 / 4; f4++) {
    float4 v = xrow[f4];
    v.x = (v.x - s_mean[f4 * 4 + 0]) * s_rstd[f4 * 4 + 0];
    v.y = (v.y - s_mean[f4 * 4 + 1]) * s_rstd[f4 * 4 + 1];
    v.z = (v.z - s_mean[f4 * 4 + 2]) * s_rstd[f4 * 4 + 2];
    v.w = (v.w - s_mean[f4 * 4 + 3]) * s_rstd[f4 * 4 + 3];
    xn[f4] = v;
  }
  const float4* wt4 = reinterpret_cast<const float4*>(s_wt);
#pragma unroll 1
  for (int h = 0; h < H0n; h++) {
    float sdot = 0.f, ddot = 0.f;
    const int base = (b * H0n + h) * Nn + n;
    float4* hpo = reinterpret_cast<float4*>(hp + (size_t)base * F1n);
#pragma unroll 1
    for (int o4 = 0; o4 < F1n / 4; o4++) {
      float a0 = 0.f, a1 = 0.f, a2 = 0.f, a3 = 0.f;
#pragma unroll
      for (int f4 = 0; f4 < F0 / 4; f4++) {
        const float4 xv  = xn[f4];
        const float4 wv0 = wt4[(h * F1n + (o4 * 4 + 0)) * (F0 / 4) + f4];
        const float4 wv1 = wt4[(h * F1n + (o4 * 4 + 1)) * (F0 / 4) + f4];
        const float4 wv2 = wt4[(h * F1n + (o4 * 4 + 2)) * (F0 / 4) + f4];
        const float4 wv3 = wt4[(h * F1n + (o4 * 4 + 3)) * (F0 / 4) + f4];
        a0 = fmaf(xv.x, wv0.x, a0); a0 = fmaf(xv.y, wv0.y, a0);
        a0 = fmaf(xv.z, wv0.z, a0); a0 = fmaf(xv.w, wv0.w, a0);
        a1 = fmaf(xv.x, wv1.x, a1); a1 = fmaf(xv.y, wv1.y, a1);
        a1 = fmaf(xv.z, wv1.z, a1); a1 = fmaf(xv.w, wv1.w, a1);
        a2 = fmaf(xv.x, wv2.x, a2); a2 = fmaf(xv.y, wv2.y, a2);
        a2 = fmaf(xv.z, wv2.z, a2); a2 = fmaf(xv.w, wv2.w, a2);
        a3 = fmaf(xv.x, wv3.x, a3); a3 = fmaf(xv.y, wv3.y, a3);
        a3 = fmaf(xv.z, wv3.z, a3); a3 = fmaf(xv.w, wv3.w, a3);
      }
      sdot = fmaf(a0, s_as[h * F1n + o4 * 4 + 0], sdot);
      sdot = fmaf(a1, s_as[h * F1n + o4 * 4 + 1], sdot);
      sdot = fmaf(a2, s_as[h * F1n + o4 * 4 + 2], sdot);
      sdot = fmaf(a3, s_as[h * F1n + o4 * 4 + 3], sdot);
      ddot = fmaf(a0, s_ad[h * F1n + o4 * 4 + 0], ddot);
      ddot = fmaf(a1, s_ad[h * F1n + o4 * 4 + 1], ddot);
      ddot = fmaf(a2, s_ad[h * F1n + o4 * 4 + 2], ddot);
      ddot = fmaf(a3, s_ad[h * F1n + o4 * 4 + 3], ddot);
      hpo[o4] = make_float4(a0, a1, a2, a3);
    }
    src[base] = sdot;
    dst[base] = ddot;
  }
}

// ---------------------------------------------------------------------------
// K2: attention layer 0 + bias + elu + transpose -> x1 [b,n,64]
// Wave-level j-parallel: lane = (r_local:8, g:8), each lane does 128 j's
// (j = jj*8+g), butterfly combine over g. Block = 4 waves = 32 rows.
// grid = 64 (b,h) * 32 tiles = 2048 blocks.
// ---------------------------------------------------------------------------
__global__ __launch_bounds__(256) void k_attn1(
    const float* __restrict__ hp, const float* __restrict__ src,
    const float* __restrict__ dst, const float* __restrict__ bias,
    float* __restrict__ x1)
{
  const int bh   = blockIdx.x >> 5;
  const int tile = blockIdx.x & 31;
  const int tid  = threadIdx.x;
  const int w    = tid >> 6;        // wave 0..3
  const int lane = tid & 63;
  const int rl   = lane >> 3;       // row-in-wave 0..7
  const int g    = lane & 7;        // j-group 0..7

  __shared__ float s_dst[Nn];
  __shared__ float s_red[256];

  const float* dp = dst + bh * Nn;
  float lm = -1e30f;
  for (int j = tid; j < Nn; j += 256) {
    float v = dp[j];
    s_dst[j] = v;
    lm = fmaxf(lm, v);
  }
  s_red[tid] = lm;
  __syncthreads();
  for (int s = 128; s > 0; s >>= 1) {
    if (tid < s) s_red[tid] = fmaxf(s_red[tid], s_red[tid + s]);
    __syncthreads();
  }
  const float dmax = s_red[0];

  const int i  = tile * 32 + w * 8 + rl;
  const float si = src[bh * Nn + i];
  const float t0 = si + dmax;
  const float m  = fmaxf(t0, ALPHA * t0);   // lrelu monotone => row max
  const float em = m * LOG2E;

  float acc[F1n];
#pragma unroll
  for (int k = 0; k < F1n; k++) acc[k] = 0.f;
  float psum = 0.f;

  const float4* hp4 = reinterpret_cast<const float4*>(hp + (size_t)bh * Nn * F1n);
#pragma unroll 4
  for (int jj = 0; jj < 128; ++jj) {
    const int j = (jj << 3) | g;
    const float tt = si + s_dst[j];
    const float u  = fmaxf(tt, ALPHA * tt);
    const float p  = exp2f(fmaf(u, LOG2E, -em));
    psum += p;
    const float4 v0 = hp4[(size_t)j * 4 + 0];
    const float4 v1 = hp4[(size_t)j * 4 + 1];
    const float4 v2 = hp4[(size_t)j * 4 + 2];
    const float4 v3 = hp4[(size_t)j * 4 + 3];
    acc[0]  = fmaf(p, v0.x, acc[0]);  acc[1]  = fmaf(p, v0.y, acc[1]);
    acc[2]  = fmaf(p, v0.z, acc[2]);  acc[3]  = fmaf(p, v0.w, acc[3]);
    acc[4]  = fmaf(p, v1.x, acc[4]);  acc[5]  = fmaf(p, v1.y, acc[5]);
    acc[6]  = fmaf(p, v1.z, acc[6]);  acc[7]  = fmaf(p, v1.w, acc[7]);
    acc[8]  = fmaf(p, v2.x, acc[8]);  acc[9]  = fmaf(p, v2.y, acc[9]);
    acc[10] = fmaf(p, v2.z, acc[10]); acc[11] = fmaf(p, v2.w, acc[11]);
    acc[12] = fmaf(p, v3.x, acc[12]); acc[13] = fmaf(p, v3.y, acc[13]);
    acc[14] = fmaf(p, v3.z, acc[14]); acc[15] = fmaf(p, v3.w, acc[15]);
  }

  // butterfly over the 8 j-groups (masks 1,2,4 stay within the octet)
#pragma unroll
  for (int mask = 1; mask < 8; mask <<= 1) {
#pragma unroll
    for (int k = 0; k < F1n; k++) acc[k] += __shfl_xor(acc[k], mask);
    psum += __shfl_xor(psum, mask);
  }

  // every lane in the octet now has the full row sums; lane g writes 2 ch.
  const float inv = 1.f / psum;
  const int b = bh >> 2, h = bh & 3;
  const int k0 = g * 2;
  float2 v;
  v.x = fmaf(acc[k0 + 0], inv, bias[k0 + 0]);
  v.y = fmaf(acc[k0 + 1], inv, bias[k0 + 1]);
  v.x = v.x > 0.f ? v.x : exp2f(v.x * LOG2E) - 1.f;   // elu
  v.y = v.y > 0.f ? v.y : exp2f(v.y * LOG2E) - 1.f;
  *reinterpret_cast<float2*>(x1 + ((size_t)(b * Nn + i)) * FH + h * F1n + k0) = v;
}

// ---------------------------------------------------------------------------
// K3: instance-norm(x1) -> h_prime2 [b,n,32], src2/dst2 [b,n]
// grid = 16 b * 4 ntiles, block = 256
// ---------------------------------------------------------------------------
__global__ __launch_bounds__(256) void k_norm_proj2(
    const float* __restrict__ x1, const float* __restrict__ w2,
    const float* __restrict__ asrc, const float* __restrict__ adst,
    float* __restrict__ hp, float* __restrict__ src, float* __restrict__ dst)
{
  const int b     = blockIdx.x >> 2;
  const int ntile = blockIdx.x & 3;
  const int tid   = threadIdx.x;

  __shared__ float s_sum[4][64];
  __shared__ float s_ssq[4][64];
  __shared__ float s_mean[64];
  __shared__ float s_rstd[64];
  __shared__ float s_wt[F2n * FH];   // transposed: [o][f]
  __shared__ float s_as[F2n];
  __shared__ float s_ad[F2n];

  for (int idx = tid; idx < F2n * FH; idx += 256) {
    const int f = idx & 63, o = idx >> 6;
    s_wt[idx] = w2[f * F2n + o];
  }
  if (tid < F2n) { s_as[tid] = asrc[tid]; s_ad[tid] = adst[tid]; }

  const float* xb = x1 + (size_t)b * Nn * FH;
  const int c = tid & 63, sub = tid >> 6;
  float sum = 0.f, ssq = 0.f;
  for (int nn = sub; nn < Nn; nn += 4) {
    float v = xb[nn * FH + c];
    sum += v; ssq += v * v;
  }
  s_sum[sub][c] = sum; s_ssq[sub][c] = ssq;
  __syncthreads();
  if (tid < 64) {
    float s = 0.f, q = 0.f;
#pragma unroll
    for (int k = 0; k < 4; k++) { s += s_sum[k][tid]; q += s_ssq[k][tid]; }
    const float mean = s * (1.f / Nn);
    const float var  = fmaf(-mean, mean, q * (1.f / Nn));
    s_mean[tid] = mean;
    s_rstd[tid] = rsqrtf(var + EPS);
  }
  __syncthreads();

  const int n = ntile * 256 + tid;
  float4 xn[FH / 4];
  const float4* xrow = reinterpret_cast<const float4*>(xb + (size_t)n * FH);
#pragma unroll
  for (int f4 = 0; f4 < FH / 4; f4++) {
    float4 v = xrow[f4];
    v.x = (v.x - s_mean[f4 * 4 + 0]) * s_rstd[f4 * 4 + 0];
    v.y = (v.y - s_mean[f4 * 4 + 1]) * s_rstd[f4 * 4 + 1];
    v.z = (v.z - s_mean[f4 * 4 + 2]) * s_rstd[f4 * 4 + 2];
    v.w = (v.w - s_mean[f4 * 4 + 3]) * s_rstd[f4 * 4 + 3];
    xn[f4] = v;
  }

  const int base = b * Nn + n;
  float4* hpo = reinterpret_cast<float4*>(hp + (size_t)base * F2n);
  const float4* wt4 = reinterpret_cast<const float4*>(s_wt);
  float sdot = 0.f, ddot = 0.f;
#pragma unroll 1
  for (int o4 = 0; o4 < F2n / 4; o4++) {
    float a0 = 0.f, a1 = 0.f, a2 = 0.f, a3 = 0.f;
#pragma unroll
    for (int f4 = 0; f4 < FH / 4; f4++) {
      const float4 xv  = xn[f4];
      const float4 wv0 = wt4[(o4 * 4 + 0) * (FH / 4) + f4];
      const float4 wv1 = wt4[(o4 * 4 + 1) * (FH / 4) + f4];
      const float4 wv2 = wt4[(o4 * 4 + 2) * (FH / 4) + f4];
      const float4 wv3 = wt4[(o4 * 4 + 3) * (FH / 4) + f4];
      a0 = fmaf(xv.x, wv0.x, a0); a0 = fmaf(xv.y, wv0.y, a0);
      a0 = fmaf(xv.z, wv0.z, a0); a0 = fmaf(xv.w, wv0.w, a0);
      a1 = fmaf(xv.x, wv1.x, a1); a1 = fmaf(xv.y, wv1.y, a1);
      a1 = fmaf(xv.z, wv1.z, a1); a1 = fmaf(xv.w, wv1.w, a1);
      a2 = fmaf(xv.x, wv2.x, a2); a2 = fmaf(xv.y, wv2.y, a2);
      a2 = fmaf(xv.z, wv2.z, a2); a2 = fmaf(xv.w, wv2.w, a2);
      a3 = fmaf(xv.x, wv3.x, a3); a3 = fmaf(xv.y, wv3.y, a3);
      a3 = fmaf(xv.z, wv3.z, a3); a3 = fmaf(xv.w, wv3.w, a3);
    }
    sdot = fmaf(a0, s_as[o4 * 4 + 0], sdot);
    sdot = fmaf(a1, s_as[o4 * 4 + 1], sdot);
    sdot = fmaf(a2, s_as[o4 * 4 + 2], sdot);
    sdot = fmaf(a3, s_as[o4 * 4 + 3], sdot);
    ddot = fmaf(a0, s_ad[o4 * 4 + 0], ddot);
    ddot = fmaf(a1, s_ad[o4 * 4 + 1], ddot);
    ddot = fmaf(a2, s_ad[o4 * 4 + 2], ddot);
    ddot = fmaf(a3, s_ad[o4 * 4 + 3], ddot);
    hpo[o4] = make_float4(a0, a1, a2, a3);
  }
  src[base] = sdot;
  dst[base] = ddot;
}

// ---------------------------------------------------------------------------
// K4: attention layer 1 + bias -> out [b,n,32]
// Wave-level j-parallel: lane = (r_local:4, g:16), each lane does 64 j's
// (j = jj*16+g), butterfly over g. Block = 4 waves = 16 rows.
// grid = 16 b * 64 tiles = 1024 blocks.
// ---------------------------------------------------------------------------
__global__ __launch_bounds__(256) void k_attn2(
    const float* __restrict__ hp, const float* __restrict__ src,
    const float* __restrict__ dst, const float* __restrict__ bias,
    float* __restrict__ out)
{
  const int b    = blockIdx.x >> 6;
  const int tile = blockIdx.x & 63;
  const int tid  = threadIdx.x;
  const int w    = tid >> 6;
  const int lane = tid & 63;
  const int rl   = lane >> 4;       // 0..3
  const int g    = lane & 15;       // j-group 0..15

  __shared__ float s_dst[Nn];
  __shared__ float s_red[256];

  const float* dp = dst + b * Nn;
  float lm = -1e30f;
  for (int j = tid; j < Nn; j += 256) {
    float v = dp[j];
    s_dst[j] = v;
    lm = fmaxf(lm, v);
  }
  s_red[tid] = lm;
  __syncthreads();
  for (int s = 128; s > 0; s >>= 1) {
    if (tid < s) s_red[tid] = fmaxf(s_red[tid], s_red[tid + s]);
    __syncthreads();
  }
  const float dmax = s_red[0];

  const int i  = tile * 16 + w * 4 + rl;
  const float si = src[b * Nn + i];
  const float t0 = si + dmax;
  const float m  = fmaxf(t0, ALPHA * t0);
  const float em = m * LOG2E;

  float acc[F2n];
#pragma unroll
  for (int k = 0; k < F2n; k++) acc[k] = 0.f;
  float psum = 0.f;

  const float4* hp4 = reinterpret_cast<const float4*>(hp + (size_t)b * Nn * F2n);
#pragma unroll 2
  for (int jj = 0; jj < 64; ++jj) {
    const int j = (jj << 4) | g;
    const float tt = si + s_dst[j];
    const float u  = fmaxf(tt, ALPHA * tt);
    const float p  = exp2f(fmaf(u, LOG2E, -em));
    psum += p;
#pragma unroll
    for (int k4 = 0; k4 < F2n / 4; k4++) {
      const float4 v = hp4[(size_t)j * 8 + k4];
      acc[k4 * 4 + 0] = fmaf(p, v.x, acc[k4 * 4 + 0]);
      acc[k4 * 4 + 1] = fmaf(p, v.y, acc[k4 * 4 + 1]);
      acc[k4 * 4 + 2] = fmaf(p, v.z, acc[k4 * 4 + 2]);
      acc[k4 * 4 + 3] = fmaf(p, v.w, acc[k4 * 4 + 3]);
    }
  }

  // butterfly over the 16 j-groups (masks 1,2,4,8 stay within the 16-group)
#pragma unroll
  for (int mask = 1; mask < 16; mask <<= 1) {
#pragma unroll
    for (int k = 0; k < F2n; k++) acc[k] += __shfl_xor(acc[k], mask);
    psum += __shfl_xor(psum, mask);
  }

  const float inv = 1.f / psum;
  const int k0 = g * 2;
  float2 v;
  v.x = fmaf(acc[k0 + 0], inv, bias[k0 + 0]);
  v.y = fmaf(acc[k0 + 1], inv, bias[k0 + 1]);
  *reinterpret_cast<float2*>(out + ((size_t)(b * Nn + i)) * F2n + k0) = v;
}

extern "C" void kernel_launch(void* const* d_in, const int* in_sizes, int n_in,
                              void* d_out, int out_size, void* d_ws, size_t ws_size,
                              hipStream_t stream) {
  (void)in_sizes; (void)n_in; (void)out_size; (void)ws_size;
  const float* x   = (const float*)d_in[0];
  const float* w1  = (const float*)d_in[1];
  const float* as1 = (const float*)d_in[2];
  const float* ad1 = (const float*)d_in[3];
  const float* b1  = (const float*)d_in[4];
  const float* w2  = (const float*)d_in[5];
  const float* as2 = (const float*)d_in[6];
  const float* ad2 = (const float*)d_in[7];
  const float* b2  = (const float*)d_in[8];
  float* out = (float*)d_out;

  float* ws   = (float*)d_ws;
  float* hp1  = ws;                    // 16*4*1024*16 = 1048576 floats
  float* src1 = hp1 + 1048576;         // 65536
  float* dst1 = src1 + 65536;          // 65536
  float* x1   = dst1 + 65536;          // 16*1024*64 = 1048576
  float* hp2  = x1 + 1048576;          // 16*1024*32 = 524288
  float* src2 = hp2 + 524288;          // 16384
  float* dst2 = src2 + 16384;          // 16384
  // total: 2,785,280 floats = 11.1 MB of workspace

  k_norm_proj1<<<64, 256, 0, stream>>>(x, w1, as1, ad1, hp1, src1, dst1);
  k_attn1<<<2048, 256, 0, stream>>>(hp1, src1, dst1, b1, x1);
  k_norm_proj2<<<64, 256, 0, stream>>>(x1, w2, as2, ad2, hp2, src2, dst2);
  k_attn2<<<1024, 256, 0, stream>>>(hp2, src2, dst2, b2, out);
}

// Round 3
// 293.295 us; speedup vs baseline: 2.2252x; 2.2252x over previous
//
#include <hip/hip_runtime.h>

// ProxemicsFieldGenerator: 2-layer GAT on dense graph.
// b=16, n=1024, f0=32, h0=4, f1=16, FH=64, f2=32, h1=1.
// Structure: stats -> proj -> attn per layer. Attention keeps j wave-uniform
// (rows across lanes) so hp loads are broadcast; occupancy comes from
// splitting j across waves and tiles across blocks.

namespace {
constexpr int Nn  = 1024;
constexpr int F0  = 32;
constexpr int F1n = 16;
constexpr int FH  = 64;   // h0 * f1
constexpr int F2n = 32;
constexpr float LOG2E = 1.4426950408889634f;
constexpr float EPS   = 1e-5f;
constexpr float ALPHA = 0.2f;
}

// ---------------------------------------------------------------------------
// Stats1: mean/rstd per (b, c) of x [16,1024,32] -> stats [b][2][32]
// grid = 16, block = 1024 (c = t&31, seg = t>>5 covers 32 rows)
// ---------------------------------------------------------------------------
__global__ __launch_bounds__(1024) void k_stats1(
    const float* __restrict__ x, float* __restrict__ stats)
{
  const int b = blockIdx.x;
  const int t = threadIdx.x;
  const int c = t & 31, seg = t >> 5;

  __shared__ float s_sum[32][33];
  __shared__ float s_ssq[32][33];

  const float* xb = x + (size_t)b * Nn * F0;
  float sum = 0.f, ssq = 0.f;
#pragma unroll 4
  for (int k = 0; k < 32; k++) {
    float v = xb[(seg * 32 + k) * F0 + c];
    sum += v; ssq += v * v;
  }
  s_sum[seg][c] = sum; s_ssq[seg][c] = ssq;
  __syncthreads();
  if (t < 32) {
    float s = 0.f, q = 0.f;
#pragma unroll
    for (int k = 0; k < 32; k++) { s += s_sum[k][t]; q += s_ssq[k][t]; }
    const float mean = s * (1.f / Nn);
    const float var  = fmaf(-mean, mean, q * (1.f / Nn));
    stats[b * 64 + t]      = mean;
    stats[b * 64 + 32 + t] = rsqrtf(var + EPS);
  }
}

// ---------------------------------------------------------------------------
// Proj1: normalize + project -> hp1 [b,h,n,16], src1/dst1 [b,h,n]
// grid = 16 b * 16 tiles(64 rows), block = 256 (r = t&63, h = t>>6)
// ---------------------------------------------------------------------------
__global__ __launch_bounds__(256, 4) void k_proj1(
    const float* __restrict__ x, const float* __restrict__ stats,
    const float* __restrict__ w1,
    const float* __restrict__ asrc, const float* __restrict__ adst,
    float* __restrict__ hp, float* __restrict__ src, float* __restrict__ dst)
{
  const int b    = blockIdx.x >> 4;
  const int tile = blockIdx.x & 15;
  const int t    = threadIdx.x;
  const int r    = t & 63, h = t >> 6;

  __shared__ float s_x[64 * 33];          // padded rows
  __shared__ float s_wt[4 * F1n * F0];    // [h][o][f]
  __shared__ float s_mean[32], s_rstd[32];
  __shared__ float s_as[64], s_ad[64];

  const float* xb = x + (size_t)b * Nn * F0 + (size_t)tile * 64 * F0;
  for (int idx = t; idx < 64 * F0; idx += 256) {
    const int rr = idx >> 5, f = idx & 31;
    s_x[rr * 33 + f] = xb[idx];
  }
  for (int idx = t; idx < 4 * F1n * F0; idx += 256) {
    const int f = idx & 31, ho = idx >> 5;
    s_wt[idx] = w1[((ho >> 4) * F0 + f) * F1n + (ho & 15)];
  }
  if (t < 32)                 s_mean[t] = stats[b * 64 + t];
  else if (t < 64)            s_rstd[t - 32] = stats[b * 64 + t];
  if (t < 64) { s_as[t] = asrc[t]; s_ad[t] = adst[t]; }
  __syncthreads();
  for (int idx = t; idx < 64 * F0; idx += 256) {
    const int rr = idx >> 5, f = idx & 31;
    s_x[rr * 33 + f] = (s_x[rr * 33 + f] - s_mean[f]) * s_rstd[f];
  }
  __syncthreads();

  const int n    = tile * 64 + r;
  const int base = (b * 4 + h) * Nn + n;
  float a[F1n];
  float sdot = 0.f, ddot = 0.f;
#pragma unroll 1
  for (int o = 0; o < F1n; o++) {
    float acc = 0.f;
#pragma unroll
    for (int f = 0; f < F0; f++)
      acc = fmaf(s_x[r * 33 + f], s_wt[(h * F1n + o) * F0 + f], acc);
    a[o] = acc;
    sdot = fmaf(acc, s_as[h * F1n + o], sdot);
    ddot = fmaf(acc, s_ad[h * F1n + o], ddot);
  }
  float4* hpo = reinterpret_cast<float4*>(hp + (size_t)base * F1n);
#pragma unroll
  for (int o4 = 0; o4 < F1n / 4; o4++)
    hpo[o4] = make_float4(a[o4 * 4], a[o4 * 4 + 1], a[o4 * 4 + 2], a[o4 * 4 + 3]);
  src[base] = sdot;
  dst[base] = ddot;
}

// ---------------------------------------------------------------------------
// Attn1 + bias + elu + transpose -> x1 [b,n,64]
// block 512 = 8 waves; wave q: rows tile*64+[0,64) x j in [q*128,(q+1)*128).
// grid = 64 bh * 16 tiles = 1024 blocks (4/CU). LDS combine, channel-split
// epilogue: thread (q,r) finalizes channels {2q, 2q+1}.
// ---------------------------------------------------------------------------
__global__ __launch_bounds__(512, 8) void k_attn1(
    const float* __restrict__ hp, const float* __restrict__ src,
    const float* __restrict__ dst, const float* __restrict__ bias,
    float* __restrict__ x1)
{
  const int bh   = blockIdx.x >> 4;
  const int tile = blockIdx.x & 15;
  const int t    = threadIdx.x;
  const int q    = t >> 6;          // wave = j-group 0..7
  const int r    = t & 63;          // row-in-tile

  __shared__ float s_dst[Nn];
  __shared__ float s_red[8];
  __shared__ float s_comb[8][64][F1n + 1];

  const float* dp = dst + bh * Nn;
  float lm = -1e30f;
  for (int j = t; j < Nn; j += 512) {
    float v = dp[j];
    s_dst[j] = v;
    lm = fmaxf(lm, v);
  }
#pragma unroll
  for (int mask = 32; mask >= 1; mask >>= 1) lm = fmaxf(lm, __shfl_xor(lm, mask));
  if (r == 0) s_red[q] = lm;
  __syncthreads();
  float dmax = s_red[0];
#pragma unroll
  for (int k = 1; k < 8; k++) dmax = fmaxf(dmax, s_red[k]);

  const int i  = tile * 64 + r;
  const float si = src[bh * Nn + i];
  const float t0 = si + dmax;
  const float m  = fmaxf(t0, ALPHA * t0);   // lrelu monotone => row max
  const float em = m * LOG2E;

  float acc[F1n];
#pragma unroll
  for (int k = 0; k < F1n; k++) acc[k] = 0.f;
  float psum = 0.f;

  const float4* hp4 = reinterpret_cast<const float4*>(hp + (size_t)bh * Nn * F1n);
  const int j0 = q * 128;
#pragma unroll 2
  for (int jj = 0; jj < 128; ++jj) {
    const int j = j0 + jj;
    const float tt = si + s_dst[j];
    const float u  = fmaxf(tt, ALPHA * tt);
    const float p  = exp2f(fmaf(u, LOG2E, -em));
    psum += p;
    const float4 v0 = hp4[(size_t)j * 4 + 0];
    const float4 v1 = hp4[(size_t)j * 4 + 1];
    const float4 v2 = hp4[(size_t)j * 4 + 2];
    const float4 v3 = hp4[(size_t)j * 4 + 3];
    acc[0]  = fmaf(p, v0.x, acc[0]);  acc[1]  = fmaf(p, v0.y, acc[1]);
    acc[2]  = fmaf(p, v0.z, acc[2]);  acc[3]  = fmaf(p, v0.w, acc[3]);
    acc[4]  = fmaf(p, v1.x, acc[4]);  acc[5]  = fmaf(p, v1.y, acc[5]);
    acc[6]  = fmaf(p, v1.z, acc[6]);  acc[7]  = fmaf(p, v1.w, acc[7]);
    acc[8]  = fmaf(p, v2.x, acc[8]);  acc[9]  = fmaf(p, v2.y, acc[9]);
    acc[10] = fmaf(p, v2.z, acc[10]); acc[11] = fmaf(p, v2.w, acc[11]);
    acc[12] = fmaf(p, v3.x, acc[12]); acc[13] = fmaf(p, v3.y, acc[13]);
    acc[14] = fmaf(p, v3.z, acc[14]); acc[15] = fmaf(p, v3.w, acc[15]);
  }

#pragma unroll
  for (int k = 0; k < F1n; k++) s_comb[q][r][k] = acc[k];
  s_comb[q][r][F1n] = psum;
  __syncthreads();

  // thread (q,r) finalizes channels 2q, 2q+1 of row i
  float a0 = 0.f, a1 = 0.f, ps = 0.f;
  const int k0 = q * 2;
#pragma unroll
  for (int g = 0; g < 8; g++) {
    a0 += s_comb[g][r][k0];
    a1 += s_comb[g][r][k0 + 1];
    ps += s_comb[g][r][F1n];
  }
  const float inv = 1.f / ps;
  const int b = bh >> 2, h = bh & 3;
  float2 v;
  v.x = fmaf(a0, inv, bias[k0 + 0]);
  v.y = fmaf(a1, inv, bias[k0 + 1]);
  v.x = v.x > 0.f ? v.x : exp2f(v.x * LOG2E) - 1.f;   // elu
  v.y = v.y > 0.f ? v.y : exp2f(v.y * LOG2E) - 1.f;
  *reinterpret_cast<float2*>(x1 + ((size_t)(b * Nn + i)) * FH + h * F1n + k0) = v;
}

// ---------------------------------------------------------------------------
// Stats2: mean/rstd per (b, c) of x1 [16,1024,64] -> stats [b][2][64]
// grid = 16, block = 1024 (c = t&63, seg = t>>6 covers 64 rows)
// ---------------------------------------------------------------------------
__global__ __launch_bounds__(1024) void k_stats2(
    const float* __restrict__ x1, float* __restrict__ stats)
{
  const int b = blockIdx.x;
  const int t = threadIdx.x;
  const int c = t & 63, seg = t >> 6;

  __shared__ float s_sum[16][65];
  __shared__ float s_ssq[16][65];

  const float* xb = x1 + (size_t)b * Nn * FH;
  float sum = 0.f, ssq = 0.f;
#pragma unroll 4
  for (int k = 0; k < 64; k++) {
    float v = xb[(seg * 64 + k) * FH + c];
    sum += v; ssq += v * v;
  }
  s_sum[seg][c] = sum; s_ssq[seg][c] = ssq;
  __syncthreads();
  if (t < 64) {
    float s = 0.f, q = 0.f;
#pragma unroll
    for (int k = 0; k < 16; k++) { s += s_sum[k][t]; q += s_ssq[k][t]; }
    const float mean = s * (1.f / Nn);
    const float var  = fmaf(-mean, mean, q * (1.f / Nn));
    stats[b * 128 + t]      = mean;
    stats[b * 128 + 64 + t] = rsqrtf(var + EPS);
  }
}

// ---------------------------------------------------------------------------
// Proj2: normalize + project -> hp2 [b,n,32], src2/dst2 [b,n]
// grid = 16 b * 16 tiles(64 rows), block = 256 (r = t&63, og = t>>6: 8 outs)
// ---------------------------------------------------------------------------
__global__ __launch_bounds__(256, 4) void k_proj2(
    const float* __restrict__ x1, const float* __restrict__ stats,
    const float* __restrict__ w2,
    const float* __restrict__ asrc, const float* __restrict__ adst,
    float* __restrict__ hp, float* __restrict__ src, float* __restrict__ dst)
{
  const int b    = blockIdx.x >> 4;
  const int tile = blockIdx.x & 15;
  const int t    = threadIdx.x;
  const int r    = t & 63, og = t >> 6;

  __shared__ float s_x[64 * 65];          // padded rows
  __shared__ float s_wt[F2n * FH];        // [o][f]
  __shared__ float s_mean[64], s_rstd[64];
  __shared__ float s_as[F2n], s_ad[F2n];
  __shared__ float s_sd[4][64][2];

  const float* xb = x1 + (size_t)b * Nn * FH + (size_t)tile * 64 * FH;
  for (int idx = t; idx < 64 * FH; idx += 256) {
    const int rr = idx >> 6, f = idx & 63;
    s_x[rr * 65 + f] = xb[idx];
  }
  for (int idx = t; idx < F2n * FH; idx += 256) {
    const int f = idx & 63, o = idx >> 6;
    s_wt[idx] = w2[f * F2n + o];
  }
  if (t < 64)                 s_mean[t] = stats[b * 128 + t];
  else if (t < 128)           s_rstd[t - 64] = stats[b * 128 + t];
  if (t < F2n) { s_as[t] = asrc[t]; s_ad[t] = adst[t]; }
  __syncthreads();
  for (int idx = t; idx < 64 * FH; idx += 256) {
    const int rr = idx >> 6, f = idx & 63;
    s_x[rr * 65 + f] = (s_x[rr * 65 + f] - s_mean[f]) * s_rstd[f];
  }
  __syncthreads();

  const int n    = tile * 64 + r;
  const int base = b * Nn + n;
  float a[8];
  float sdot = 0.f, ddot = 0.f;
#pragma unroll 1
  for (int oo = 0; oo < 8; oo++) {
    const int o = og * 8 + oo;
    float acc = 0.f;
#pragma unroll
    for (int f = 0; f < FH; f++)
      acc = fmaf(s_x[r * 65 + f], s_wt[o * FH + f], acc);
    a[oo] = acc;
    sdot = fmaf(acc, s_as[o], sdot);
    ddot = fmaf(acc, s_ad[o], ddot);
  }
  float4* hpo = reinterpret_cast<float4*>(hp + (size_t)base * F2n + og * 8);
  hpo[0] = make_float4(a[0], a[1], a[2], a[3]);
  hpo[1] = make_float4(a[4], a[5], a[6], a[7]);

  s_sd[og][r][0] = sdot; s_sd[og][r][1] = ddot;
  __syncthreads();
  if (og == 0) {
    float s = 0.f, d = 0.f;
#pragma unroll
    for (int g = 0; g < 4; g++) { s += s_sd[g][r][0]; d += s_sd[g][r][1]; }
    src[base] = s;
    dst[base] = d;
  }
}

// ---------------------------------------------------------------------------
// Attn2 + bias -> out [b,n,32]
// block 512 = 8 waves; wave q: rows tile*64+[0,64) x j in [q*128,(q+1)*128).
// grid = 16 b * 16 tiles = 256 blocks. Channel-split epilogue: thread (q,r)
// finalizes channels 4q..4q+3.
// ---------------------------------------------------------------------------
__global__ __launch_bounds__(512, 2) void k_attn2(
    const float* __restrict__ hp, const float* __restrict__ src,
    const float* __restrict__ dst, const float* __restrict__ bias,
    float* __restrict__ out)
{
  const int b    = blockIdx.x >> 4;
  const int tile = blockIdx.x & 15;
  const int t    = threadIdx.x;
  const int q    = t >> 6;
  const int r    = t & 63;

  __shared__ float s_dst[Nn];
  __shared__ float s_red[8];
  __shared__ float s_comb[8][64][F2n + 1];

  const float* dp = dst + b * Nn;
  float lm = -1e30f;
  for (int j = t; j < Nn; j += 512) {
    float v = dp[j];
    s_dst[j] = v;
    lm = fmaxf(lm, v);
  }
#pragma unroll
  for (int mask = 32; mask >= 1; mask >>= 1) lm = fmaxf(lm, __shfl_xor(lm, mask));
  if (r == 0) s_red[q] = lm;
  __syncthreads();
  float dmax = s_red[0];
#pragma unroll
  for (int k = 1; k < 8; k++) dmax = fmaxf(dmax, s_red[k]);

  const int i  = tile * 64 + r;
  const float si = src[b * Nn + i];
  const float t0 = si + dmax;
  const float m  = fmaxf(t0, ALPHA * t0);
  const float em = m * LOG2E;

  float acc[F2n];
#pragma unroll
  for (int k = 0; k < F2n; k++) acc[k] = 0.f;
  float psum = 0.f;

  const float4* hp4 = reinterpret_cast<const float4*>(hp + (size_t)b * Nn * F2n);
  const int j0 = q * 128;
#pragma unroll 2
  for (int jj = 0; jj < 128; ++jj) {
    const int j = j0 + jj;
    const float tt = si + s_dst[j];
    const float u  = fmaxf(tt, ALPHA * tt);
    const float p  = exp2f(fmaf(u, LOG2E, -em));
    psum += p;
#pragma unroll
    for (int k4 = 0; k4 < F2n / 4; k4++) {
      const float4 v = hp4[(size_t)j * 8 + k4];
      acc[k4 * 4 + 0] = fmaf(p, v.x, acc[k4 * 4 + 0]);
      acc[k4 * 4 + 1] = fmaf(p, v.y, acc[k4 * 4 + 1]);
      acc[k4 * 4 + 2] = fmaf(p, v.z, acc[k4 * 4 + 2]);
      acc[k4 * 4 + 3] = fmaf(p, v.w, acc[k4 * 4 + 3]);
    }
  }

#pragma unroll
  for (int k = 0; k < F2n; k++) s_comb[q][r][k] = acc[k];
  s_comb[q][r][F2n] = psum;
  __syncthreads();

  float a[4] = {0.f, 0.f, 0.f, 0.f};
  float ps = 0.f;
  const int k0 = q * 4;
#pragma unroll
  for (int g = 0; g < 8; g++) {
    a[0] += s_comb[g][r][k0 + 0];
    a[1] += s_comb[g][r][k0 + 1];
    a[2] += s_comb[g][r][k0 + 2];
    a[3] += s_comb[g][r][k0 + 3];
    ps   += s_comb[g][r][F2n];
  }
  const float inv = 1.f / ps;
  float4 v;
  v.x = fmaf(a[0], inv, bias[k0 + 0]);
  v.y = fmaf(a[1], inv, bias[k0 + 1]);
  v.z = fmaf(a[2], inv, bias[k0 + 2]);
  v.w = fmaf(a[3], inv, bias[k0 + 3]);
  *reinterpret_cast<float4*>(out + ((size_t)(b * Nn + i)) * F2n + k0) = v;
}

extern "C" void kernel_launch(void* const* d_in, const int* in_sizes, int n_in,
                              void* d_out, int out_size, void* d_ws, size_t ws_size,
                              hipStream_t stream) {
  (void)in_sizes; (void)n_in; (void)out_size; (void)ws_size;
  const float* x   = (const float*)d_in[0];
  const float* w1  = (const float*)d_in[1];
  const float* as1 = (const float*)d_in[2];
  const float* ad1 = (const float*)d_in[3];
  const float* b1  = (const float*)d_in[4];
  const float* w2  = (const float*)d_in[5];
  const float* as2 = (const float*)d_in[6];
  const float* ad2 = (const float*)d_in[7];
  const float* b2  = (const float*)d_in[8];
  float* out = (float*)d_out;

  float* ws     = (float*)d_ws;
  float* hp1    = ws;                    // 16*4*1024*16 = 1048576 floats
  float* src1   = hp1 + 1048576;         // 65536
  float* dst1   = src1 + 65536;          // 65536
  float* x1     = dst1 + 65536;          // 16*1024*64 = 1048576
  float* hp2    = x1 + 1048576;          // 16*1024*32 = 524288
  float* src2   = hp2 + 524288;          // 16384
  float* dst2   = src2 + 16384;          // 16384
  float* stats1 = dst2 + 16384;          // 16*64 = 1024
  float* stats2 = stats1 + 1024;         // 16*128 = 2048
  // total: ~2.79M floats = 11.2 MB of workspace

  k_stats1<<<16, 1024, 0, stream>>>(x, stats1);
  k_proj1<<<256, 256, 0, stream>>>(x, stats1, w1, as1, ad1, hp1, src1, dst1);
  k_attn1<<<1024, 512, 0, stream>>>(hp1, src1, dst1, b1, x1);
  k_stats2<<<16, 1024, 0, stream>>>(x1, stats2);
  k_proj2<<<256, 256, 0, stream>>>(x1, stats2, w2, as2, ad2, hp2, src2, dst2);
  k_attn2<<<256, 512, 0, stream>>>(hp2, src2, dst2, b2, out);
}

// Round 4
// 178.806 us; speedup vs baseline: 3.6500x; 1.6403x over previous
//
#include <hip/hip_runtime.h>

// ProxemicsFieldGenerator: 2-layer GAT on dense graph.
// b=16, n=1024, f0=32, h0=4, f1=16, FH=64, f2=32, h1=1.
// Attention: rows across lanes, j wave-uniform. hp[j,:] is loaded via the
// SCALAR pipe (readfirstlane-uniform address -> s_load), since broadcast
// vector loads were the per-CU VMEM throughput bottleneck (R1/R3 ~132us).

namespace {
constexpr int Nn  = 1024;
constexpr int F0  = 32;
constexpr int F1n = 16;
constexpr int FH  = 64;   // h0 * f1
constexpr int F2n = 32;
constexpr float LOG2E = 1.4426950408889634f;
constexpr float EPS   = 1e-5f;
constexpr float ALPHA = 0.2f;
}

// ---------------------------------------------------------------------------
// Stats1: mean/rstd per (b, c) of x [16,1024,32] -> stats [b][2][32]
// ---------------------------------------------------------------------------
__global__ __launch_bounds__(1024) void k_stats1(
    const float* __restrict__ x, float* __restrict__ stats)
{
  const int b = blockIdx.x;
  const int t = threadIdx.x;
  const int c = t & 31, seg = t >> 5;

  __shared__ float s_sum[32][33];
  __shared__ float s_ssq[32][33];

  const float* xb = x + (size_t)b * Nn * F0;
  float sum = 0.f, ssq = 0.f;
#pragma unroll 4
  for (int k = 0; k < 32; k++) {
    float v = xb[(seg * 32 + k) * F0 + c];
    sum += v; ssq += v * v;
  }
  s_sum[seg][c] = sum; s_ssq[seg][c] = ssq;
  __syncthreads();
  if (t < 32) {
    float s = 0.f, q = 0.f;
#pragma unroll
    for (int k = 0; k < 32; k++) { s += s_sum[k][t]; q += s_ssq[k][t]; }
    const float mean = s * (1.f / Nn);
    const float var  = fmaf(-mean, mean, q * (1.f / Nn));
    stats[b * 64 + t]      = mean;
    stats[b * 64 + 32 + t] = rsqrtf(var + EPS);
  }
}

// ---------------------------------------------------------------------------
// Proj1: normalize + project -> hp1 [b,h,n,16], src1/dst1 [b,h,n]
// grid = 16 b * 16 tiles(64 rows), block = 256 (r = t&63, h = t>>6)
// ---------------------------------------------------------------------------
__global__ __launch_bounds__(256, 4) void k_proj1(
    const float* __restrict__ x, const float* __restrict__ stats,
    const float* __restrict__ w1,
    const float* __restrict__ asrc, const float* __restrict__ adst,
    float* __restrict__ hp, float* __restrict__ src, float* __restrict__ dst)
{
  const int b    = blockIdx.x >> 4;
  const int tile = blockIdx.x & 15;
  const int t    = threadIdx.x;
  const int r    = t & 63, h = t >> 6;

  __shared__ float s_x[64 * 33];          // padded rows
  __shared__ float s_wt[4 * F1n * F0];    // [h][o][f]
  __shared__ float s_mean[32], s_rstd[32];
  __shared__ float s_as[64], s_ad[64];

  const float* xb = x + (size_t)b * Nn * F0 + (size_t)tile * 64 * F0;
  for (int idx = t; idx < 64 * F0; idx += 256) {
    const int rr = idx >> 5, f = idx & 31;
    s_x[rr * 33 + f] = xb[idx];
  }
  for (int idx = t; idx < 4 * F1n * F0; idx += 256) {
    const int f = idx & 31, ho = idx >> 5;
    s_wt[idx] = w1[((ho >> 4) * F0 + f) * F1n + (ho & 15)];
  }
  if (t < 32)                 s_mean[t] = stats[b * 64 + t];
  else if (t < 64)            s_rstd[t - 32] = stats[b * 64 + t];
  if (t < 64) { s_as[t] = asrc[t]; s_ad[t] = adst[t]; }
  __syncthreads();
  for (int idx = t; idx < 64 * F0; idx += 256) {
    const int rr = idx >> 5, f = idx & 31;
    s_x[rr * 33 + f] = (s_x[rr * 33 + f] - s_mean[f]) * s_rstd[f];
  }
  __syncthreads();

  const int n    = tile * 64 + r;
  const int base = (b * 4 + h) * Nn + n;
  float a[F1n];
  float sdot = 0.f, ddot = 0.f;
#pragma unroll 1
  for (int o = 0; o < F1n; o++) {
    float acc = 0.f;
#pragma unroll
    for (int f = 0; f < F0; f++)
      acc = fmaf(s_x[r * 33 + f], s_wt[(h * F1n + o) * F0 + f], acc);
    a[o] = acc;
    sdot = fmaf(acc, s_as[h * F1n + o], sdot);
    ddot = fmaf(acc, s_ad[h * F1n + o], ddot);
  }
  float4* hpo = reinterpret_cast<float4*>(hp + (size_t)base * F1n);
#pragma unroll
  for (int o4 = 0; o4 < F1n / 4; o4++)
    hpo[o4] = make_float4(a[o4 * 4], a[o4 * 4 + 1], a[o4 * 4 + 2], a[o4 * 4 + 3]);
  src[base] = sdot;
  dst[base] = ddot;
}

// ---------------------------------------------------------------------------
// Attn1 + bias + elu + transpose -> x1 [b,n,64]
// block 512 = 8 waves; wave q: rows tile*64+[0,64) x j in [q*128,(q+1)*128).
// grid = 64 bh * 16 tiles = 1024 blocks. hp row loads via SCALAR pipe.
// ---------------------------------------------------------------------------
__global__ __launch_bounds__(512, 8) void k_attn1(
    const float* __restrict__ hp, const float* __restrict__ src,
    const float* __restrict__ dst, const float* __restrict__ bias,
    float* __restrict__ x1)
{
  const int bh   = blockIdx.x >> 4;
  const int tile = blockIdx.x & 15;
  const int t    = threadIdx.x;
  const int q    = t >> 6;          // wave = j-group 0..7
  const int r    = t & 63;          // row-in-tile

  __shared__ float s_dst[Nn];
  __shared__ float s_red[8];
  __shared__ float s_comb[8][64][F1n + 1];

  const float* dp = dst + bh * Nn;
  float lm = -1e30f;
  for (int j = t; j < Nn; j += 512) {
    float v = dp[j];
    s_dst[j] = v;
    lm = fmaxf(lm, v);
  }
#pragma unroll
  for (int mask = 32; mask >= 1; mask >>= 1) lm = fmaxf(lm, __shfl_xor(lm, mask));
  if (r == 0) s_red[q] = lm;
  __syncthreads();
  float dmax = s_red[0];
#pragma unroll
  for (int k = 1; k < 8; k++) dmax = fmaxf(dmax, s_red[k]);

  const int i  = tile * 64 + r;
  const float si = src[bh * Nn + i];
  const float t0 = si + dmax;
  const float m  = fmaxf(t0, ALPHA * t0);   // lrelu monotone => row max
  const float em = m * LOG2E;

  float acc[F1n];
#pragma unroll
  for (int k = 0; k < F1n; k++) acc[k] = 0.f;
  float psum = 0.f;

  // uniform j => uniform hp address => scalar loads (off the VMEM pipe)
  const int jbase = __builtin_amdgcn_readfirstlane(q << 7);
  const float* __restrict__ vbase = hp + (size_t)bh * Nn * F1n;
#pragma unroll 4
  for (int jj = 0; jj < 128; ++jj) {
    const int j = jbase + jj;
    const float tt = si + s_dst[j];
    const float u  = fmaxf(tt, ALPHA * tt);
    const float p  = exp2f(fmaf(u, LOG2E, -em));
    psum += p;
    const float* vp = vbase + (size_t)j * F1n;
#pragma unroll
    for (int f = 0; f < F1n; f++) acc[f] = fmaf(p, vp[f], acc[f]);
  }

#pragma unroll
  for (int k = 0; k < F1n; k++) s_comb[q][r][k] = acc[k];
  s_comb[q][r][F1n] = psum;
  __syncthreads();

  // thread (q,r) finalizes channels 2q, 2q+1 of row i
  float a0 = 0.f, a1 = 0.f, ps = 0.f;
  const int k0 = q * 2;
#pragma unroll
  for (int g = 0; g < 8; g++) {
    a0 += s_comb[g][r][k0];
    a1 += s_comb[g][r][k0 + 1];
    ps += s_comb[g][r][F1n];
  }
  const float inv = 1.f / ps;
  const int b = bh >> 2, h = bh & 3;
  float2 v;
  v.x = fmaf(a0, inv, bias[k0 + 0]);
  v.y = fmaf(a1, inv, bias[k0 + 1]);
  v.x = v.x > 0.f ? v.x : exp2f(v.x * LOG2E) - 1.f;   // elu
  v.y = v.y > 0.f ? v.y : exp2f(v.y * LOG2E) - 1.f;
  *reinterpret_cast<float2*>(x1 + ((size_t)(b * Nn + i)) * FH + h * F1n + k0) = v;
}

// ---------------------------------------------------------------------------
// Stats2: mean/rstd per (b, c) of x1 [16,1024,64] -> stats [b][2][64]
// ---------------------------------------------------------------------------
__global__ __launch_bounds__(1024) void k_stats2(
    const float* __restrict__ x1, float* __restrict__ stats)
{
  const int b = blockIdx.x;
  const int t = threadIdx.x;
  const int c = t & 63, seg = t >> 6;

  __shared__ float s_sum[16][65];
  __shared__ float s_ssq[16][65];

  const float* xb = x1 + (size_t)b * Nn * FH;
  float sum = 0.f, ssq = 0.f;
#pragma unroll 4
  for (int k = 0; k < 64; k++) {
    float v = xb[(seg * 64 + k) * FH + c];
    sum += v; ssq += v * v;
  }
  s_sum[seg][c] = sum; s_ssq[seg][c] = ssq;
  __syncthreads();
  if (t < 64) {
    float s = 0.f, q = 0.f;
#pragma unroll
    for (int k = 0; k < 16; k++) { s += s_sum[k][t]; q += s_ssq[k][t]; }
    const float mean = s * (1.f / Nn);
    const float var  = fmaf(-mean, mean, q * (1.f / Nn));
    stats[b * 128 + t]      = mean;
    stats[b * 128 + 64 + t] = rsqrtf(var + EPS);
  }
}

// ---------------------------------------------------------------------------
// Proj2: normalize + project -> hp2 [b,n,32], src2/dst2 [b,n]
// grid = 16 b * 16 tiles(64 rows), block = 256 (r = t&63, og = t>>6)
// ---------------------------------------------------------------------------
__global__ __launch_bounds__(256, 4) void k_proj2(
    const float* __restrict__ x1, const float* __restrict__ stats,
    const float* __restrict__ w2,
    const float* __restrict__ asrc, const float* __restrict__ adst,
    float* __restrict__ hp, float* __restrict__ src, float* __restrict__ dst)
{
  const int b    = blockIdx.x >> 4;
  const int tile = blockIdx.x & 15;
  const int t    = threadIdx.x;
  const int r    = t & 63, og = t >> 6;

  __shared__ float s_x[64 * 65];          // padded rows
  __shared__ float s_wt[F2n * FH];        // [o][f]
  __shared__ float s_mean[64], s_rstd[64];
  __shared__ float s_as[F2n], s_ad[F2n];
  __shared__ float s_sd[4][64][2];

  const float* xb = x1 + (size_t)b * Nn * FH + (size_t)tile * 64 * FH;
  for (int idx = t; idx < 64 * FH; idx += 256) {
    const int rr = idx >> 6, f = idx & 63;
    s_x[rr * 65 + f] = xb[idx];
  }
  for (int idx = t; idx < F2n * FH; idx += 256) {
    const int f = idx & 63, o = idx >> 6;
    s_wt[idx] = w2[f * F2n + o];
  }
  if (t < 64)                 s_mean[t] = stats[b * 128 + t];
  else if (t < 128)           s_rstd[t - 64] = stats[b * 128 + t];
  if (t < F2n) { s_as[t] = asrc[t]; s_ad[t] = adst[t]; }
  __syncthreads();
  for (int idx = t; idx < 64 * FH; idx += 256) {
    const int rr = idx >> 6, f = idx & 63;
    s_x[rr * 65 + f] = (s_x[rr * 65 + f] - s_mean[f]) * s_rstd[f];
  }
  __syncthreads();

  const int n    = tile * 64 + r;
  const int base = b * Nn + n;
  float a[8];
  float sdot = 0.f, ddot = 0.f;
#pragma unroll 1
  for (int oo = 0; oo < 8; oo++) {
    const int o = og * 8 + oo;
    float acc = 0.f;
#pragma unroll
    for (int f = 0; f < FH; f++)
      acc = fmaf(s_x[r * 65 + f], s_wt[o * FH + f], acc);
    a[oo] = acc;
    sdot = fmaf(acc, s_as[o], sdot);
    ddot = fmaf(acc, s_ad[o], ddot);
  }
  float4* hpo = reinterpret_cast<float4*>(hp + (size_t)base * F2n + og * 8);
  hpo[0] = make_float4(a[0], a[1], a[2], a[3]);
  hpo[1] = make_float4(a[4], a[5], a[6], a[7]);

  s_sd[og][r][0] = sdot; s_sd[og][r][1] = ddot;
  __syncthreads();
  if (og == 0) {
    float s = 0.f, d = 0.f;
#pragma unroll
    for (int g = 0; g < 4; g++) { s += s_sd[g][r][0]; d += s_sd[g][r][1]; }
    src[base] = s;
    dst[base] = d;
  }
}

// ---------------------------------------------------------------------------
// Attn2 + bias -> out [b,n,32]
// block 512 = 8 waves; wave q: rows tile*64+[0,64) x j in [q*128,(q+1)*128).
// grid = 16 b * 16 tiles = 256 blocks. hp row loads via SCALAR pipe.
// ---------------------------------------------------------------------------
__global__ __launch_bounds__(512, 2) void k_attn2(
    const float* __restrict__ hp, const float* __restrict__ src,
    const float* __restrict__ dst, const float* __restrict__ bias,
    float* __restrict__ out)
{
  const int b    = blockIdx.x >> 4;
  const int tile = blockIdx.x & 15;
  const int t    = threadIdx.x;
  const int q    = t >> 6;
  const int r    = t & 63;

  __shared__ float s_dst[Nn];
  __shared__ float s_red[8];
  __shared__ float s_comb[8][64][F2n + 1];

  const float* dp = dst + b * Nn;
  float lm = -1e30f;
  for (int j = t; j < Nn; j += 512) {
    float v = dp[j];
    s_dst[j] = v;
    lm = fmaxf(lm, v);
  }
#pragma unroll
  for (int mask = 32; mask >= 1; mask >>= 1) lm = fmaxf(lm, __shfl_xor(lm, mask));
  if (r == 0) s_red[q] = lm;
  __syncthreads();
  float dmax = s_red[0];
#pragma unroll
  for (int k = 1; k < 8; k++) dmax = fmaxf(dmax, s_red[k]);

  const int i  = tile * 64 + r;
  const float si = src[b * Nn + i];
  const float t0 = si + dmax;
  const float m  = fmaxf(t0, ALPHA * t0);
  const float em = m * LOG2E;

  float acc[F2n];
#pragma unroll
  for (int k = 0; k < F2n; k++) acc[k] = 0.f;
  float psum = 0.f;

  const int jbase = __builtin_amdgcn_readfirstlane(q << 7);
  const float* __restrict__ vbase = hp + (size_t)b * Nn * F2n;
#pragma unroll 2
  for (int jj = 0; jj < 128; ++jj) {
    const int j = jbase + jj;
    const float tt = si + s_dst[j];
    const float u  = fmaxf(tt, ALPHA * tt);
    const float p  = exp2f(fmaf(u, LOG2E, -em));
    psum += p;
    const float* vp = vbase + (size_t)j * F2n;
#pragma unroll
    for (int f = 0; f < F2n; f++) acc[f] = fmaf(p, vp[f], acc[f]);
  }

#pragma unroll
  for (int k = 0; k < F2n; k++) s_comb[q][r][k] = acc[k];
  s_comb[q][r][F2n] = psum;
  __syncthreads();

  float a[4] = {0.f, 0.f, 0.f, 0.f};
  float ps = 0.f;
  const int k0 = q * 4;
#pragma unroll
  for (int g = 0; g < 8; g++) {
    a[0] += s_comb[g][r][k0 + 0];
    a[1] += s_comb[g][r][k0 + 1];
    a[2] += s_comb[g][r][k0 + 2];
    a[3] += s_comb[g][r][k0 + 3];
    ps   += s_comb[g][r][F2n];
  }
  const float inv = 1.f / ps;
  float4 v;
  v.x = fmaf(a[0], inv, bias[k0 + 0]);
  v.y = fmaf(a[1], inv, bias[k0 + 1]);
  v.z = fmaf(a[2], inv, bias[k0 + 2]);
  v.w = fmaf(a[3], inv, bias[k0 + 3]);
  *reinterpret_cast<float4*>(out + ((size_t)(b * Nn + i)) * F2n + k0) = v;
}

extern "C" void kernel_launch(void* const* d_in, const int* in_sizes, int n_in,
                              void* d_out, int out_size, void* d_ws, size_t ws_size,
                              hipStream_t stream) {
  (void)in_sizes; (void)n_in; (void)out_size; (void)ws_size;
  const float* x   = (const float*)d_in[0];
  const float* w1  = (const float*)d_in[1];
  const float* as1 = (const float*)d_in[2];
  const float* ad1 = (const float*)d_in[3];
  const float* b1  = (const float*)d_in[4];
  const float* w2  = (const float*)d_in[5];
  const float* as2 = (const float*)d_in[6];
  const float* ad2 = (const float*)d_in[7];
  const float* b2  = (const float*)d_in[8];
  float* out = (float*)d_out;

  float* ws     = (float*)d_ws;
  float* hp1    = ws;                    // 16*4*1024*16 = 1048576 floats
  float* src1   = hp1 + 1048576;         // 65536
  float* dst1   = src1 + 65536;          // 65536
  float* x1     = dst1 + 65536;          // 16*1024*64 = 1048576
  float* hp2    = x1 + 1048576;          // 16*1024*32 = 524288
  float* src2   = hp2 + 524288;          // 16384
  float* dst2   = src2 + 16384;          // 16384
  float* stats1 = dst2 + 16384;          // 16*64 = 1024
  float* stats2 = stats1 + 1024;         // 16*128 = 2048

  k_stats1<<<16, 1024, 0, stream>>>(x, stats1);
  k_proj1<<<256, 256, 0, stream>>>(x, stats1, w1, as1, ad1, hp1, src1, dst1);
  k_attn1<<<1024, 512, 0, stream>>>(hp1, src1, dst1, b1, x1);
  k_stats2<<<16, 1024, 0, stream>>>(x1, stats2);
  k_proj2<<<256, 256, 0, stream>>>(x1, stats2, w2, as2, ad2, hp2, src2, dst2);
  k_attn2<<<256, 512, 0, stream>>>(hp2, src2, dst2, b2, out);
}

// Round 6
// 152.777 us; speedup vs baseline: 4.2719x; 1.1704x over previous
//
#include <hip/hip_runtime.h>

// ProxemicsFieldGenerator: 2-layer GAT on dense graph.
// b=16, n=1024, f0=32, h0=4, f1=16, FH=64, f2=32, h1=1.
// Attention: softmax weights p in f32 (logit trick), PV on the MATRIX pipe
// with fp16 MFMA. Precision recovery vs R5 (bf16, absmax 0.44):
//  - A operand (p) in fp16 (eps 2^-11), psum computed from ROUNDED p-hat so
//    peaked rows cancel exactly;
//  - B operand (V=h_prime) split into fp16 hi+lo (two MFMAs, eps ~2^-22).

namespace {
constexpr int Nn  = 1024;
constexpr int F0  = 32;
constexpr int F1n = 16;
constexpr int FH  = 64;   // h0 * f1
constexpr int F2n = 32;
constexpr float LOG2E = 1.4426950408889634f;
constexpr float EPS   = 1e-5f;
constexpr float ALPHA = 0.2f;
}

typedef __attribute__((ext_vector_type(8))) _Float16 half8;
typedef __attribute__((ext_vector_type(4))) float f32x4;

// ---------------------------------------------------------------------------
// Stats1: mean/rstd per (b, c) of x [16,1024,32] -> stats [b][2][32]
// ---------------------------------------------------------------------------
__global__ __launch_bounds__(1024) void k_stats1(
    const float* __restrict__ x, float* __restrict__ stats)
{
  const int b = blockIdx.x;
  const int t = threadIdx.x;
  const int c = t & 31, seg = t >> 5;

  __shared__ float s_sum[32][33];
  __shared__ float s_ssq[32][33];

  const float* xb = x + (size_t)b * Nn * F0;
  float sum = 0.f, ssq = 0.f;
#pragma unroll 4
  for (int k = 0; k < 32; k++) {
    float v = xb[(seg * 32 + k) * F0 + c];
    sum += v; ssq += v * v;
  }
  s_sum[seg][c] = sum; s_ssq[seg][c] = ssq;
  __syncthreads();
  if (t < 32) {
    float s = 0.f, q = 0.f;
#pragma unroll
    for (int k = 0; k < 32; k++) { s += s_sum[k][t]; q += s_ssq[k][t]; }
    const float mean = s * (1.f / Nn);
    const float var  = fmaf(-mean, mean, q * (1.f / Nn));
    stats[b * 64 + t]      = mean;
    stats[b * 64 + 32 + t] = rsqrtf(var + EPS);
  }
}

// ---------------------------------------------------------------------------
// Proj1: normalize + project -> hpT1 hi/lo fp16 [bh][16ch][1024n], src1/dst1
// grid = 16 b * 16 tiles(64 rows), block = 256 (r = t&63, h = t>>6)
// ---------------------------------------------------------------------------
__global__ __launch_bounds__(256, 4) void k_proj1(
    const float* __restrict__ x, const float* __restrict__ stats,
    const float* __restrict__ w1,
    const float* __restrict__ asrc, const float* __restrict__ adst,
    short* __restrict__ hpT_hi, short* __restrict__ hpT_lo,
    float* __restrict__ src, float* __restrict__ dst)
{
  const int b    = blockIdx.x >> 4;
  const int tile = blockIdx.x & 15;
  const int t    = threadIdx.x;
  const int r    = t & 63, h = t >> 6;

  __shared__ float s_x[64 * 33];          // padded rows
  __shared__ float s_wt[4 * F1n * F0];    // [h][o][f]
  __shared__ float s_mean[32], s_rstd[32];
  __shared__ float s_as[64], s_ad[64];

  const float* xb = x + (size_t)b * Nn * F0 + (size_t)tile * 64 * F0;
  for (int idx = t; idx < 64 * F0; idx += 256) {
    const int rr = idx >> 5, f = idx & 31;
    s_x[rr * 33 + f] = xb[idx];
  }
  for (int idx = t; idx < 4 * F1n * F0; idx += 256) {
    const int f = idx & 31, ho = idx >> 5;
    s_wt[idx] = w1[((ho >> 4) * F0 + f) * F1n + (ho & 15)];
  }
  if (t < 32)                 s_mean[t] = stats[b * 64 + t];
  else if (t < 64)            s_rstd[t - 32] = stats[b * 64 + t];
  if (t < 64) { s_as[t] = asrc[t]; s_ad[t] = adst[t]; }
  __syncthreads();
  for (int idx = t; idx < 64 * F0; idx += 256) {
    const int rr = idx >> 5, f = idx & 31;
    s_x[rr * 33 + f] = (s_x[rr * 33 + f] - s_mean[f]) * s_rstd[f];
  }
  __syncthreads();

  const int n    = tile * 64 + r;
  const int bh   = b * 4 + h;
  float sdot = 0.f, ddot = 0.f;
#pragma unroll 1
  for (int o = 0; o < F1n; o++) {
    float acc = 0.f;
#pragma unroll
    for (int f = 0; f < F0; f++)
      acc = fmaf(s_x[r * 33 + f], s_wt[(h * F1n + o) * F0 + f], acc);
    sdot = fmaf(acc, s_as[h * F1n + o], sdot);
    ddot = fmaf(acc, s_ad[h * F1n + o], ddot);
    const _Float16 hh = (_Float16)acc;
    const _Float16 hl = (_Float16)(acc - (float)hh);
    const size_t idx = ((size_t)bh * F1n + o) * Nn + n;
    hpT_hi[idx] = __builtin_bit_cast(short, hh);
    hpT_lo[idx] = __builtin_bit_cast(short, hl);
  }
  src[bh * Nn + n] = sdot;
  dst[bh * Nn + n] = ddot;
}

// ---------------------------------------------------------------------------
// Attn1 (fp16 MFMA PV, V hi+lo) + bias + elu + transpose -> x1 [b,n,64]
// grid = 64 bh * 16 tiles = 1024 blocks, block 256 = 4 waves x 16 rows.
// Lane l: A-row/out-col = l&15, k-slot = l>>4. Full K=1024 (32 k-blocks/wave).
// ---------------------------------------------------------------------------
__global__ __launch_bounds__(256) void k_attn1(
    const short* __restrict__ hpT_hi, const short* __restrict__ hpT_lo,
    const float* __restrict__ src, const float* __restrict__ dst,
    const float* __restrict__ bias, float* __restrict__ x1)
{
  const int bh   = blockIdx.x >> 4;
  const int tile = blockIdx.x & 15;
  const int t    = threadIdx.x;
  const int w    = t >> 6;
  const int l    = t & 63;
  const int col  = l & 15;      // A-row (= query row) and C/D col (= channel)
  const int ks   = l >> 4;      // k-slot 0..3

  __shared__ float s_dst[Nn];
  __shared__ float s_red[4];
  __shared__ float s_ps[4][16];

  const float* dp = dst + bh * Nn;
  float lm = -1e30f;
  for (int j = t; j < Nn; j += 256) { float v = dp[j]; s_dst[j] = v; lm = fmaxf(lm, v); }
#pragma unroll
  for (int mask = 32; mask >= 1; mask >>= 1) lm = fmaxf(lm, __shfl_xor(lm, mask));
  if (l == 0) s_red[w] = lm;
  __syncthreads();
  const float dmax = fmaxf(fmaxf(s_red[0], s_red[1]), fmaxf(s_red[2], s_red[3]));

  const int i0 = tile * 64 + w * 16;
  const float si = src[bh * Nn + i0 + col];
  const float t0v = si + dmax;
  const float em  = fmaxf(t0v, ALPHA * t0v) * LOG2E;   // lrelu monotone => row max

  auto pexp = [&](float dv) {
    const float tt = si + dv;
    const float u  = fmaxf(tt, ALPHA * tt);
    return exp2f(fmaf(u, LOG2E, -em));
  };

  const half8* bph = reinterpret_cast<const half8*>(hpT_hi + (size_t)bh * F1n * Nn);
  const half8* bpl = reinterpret_cast<const half8*>(hpT_lo + (size_t)bh * F1n * Nn);
  f32x4 acc = {0.f, 0.f, 0.f, 0.f};
  float psum = 0.f;

#pragma unroll 2
  for (int jb = 0; jb < 32; ++jb) {
    const int jo = (jb << 5) | (ks << 3);
    const float4 dA = *reinterpret_cast<const float4*>(&s_dst[jo]);
    const float4 dB = *reinterpret_cast<const float4*>(&s_dst[jo + 4]);
    half8 af;
    const _Float16 q0 = (_Float16)pexp(dA.x); af[0] = q0;
    const _Float16 q1 = (_Float16)pexp(dA.y); af[1] = q1;
    const _Float16 q2 = (_Float16)pexp(dA.z); af[2] = q2;
    const _Float16 q3 = (_Float16)pexp(dA.w); af[3] = q3;
    const _Float16 q4 = (_Float16)pexp(dB.x); af[4] = q4;
    const _Float16 q5 = (_Float16)pexp(dB.y); af[5] = q5;
    const _Float16 q6 = (_Float16)pexp(dB.z); af[6] = q6;
    const _Float16 q7 = (_Float16)pexp(dB.w); af[7] = q7;
    // psum from the ROUNDED weights => consistent normalization
    psum += (((float)q0 + (float)q1) + ((float)q2 + (float)q3)) +
            (((float)q4 + (float)q5) + ((float)q6 + (float)q7));

    const half8 bh8 = bph[col * 128 + (jb << 2) + ks];
    const half8 bl8 = bpl[col * 128 + (jb << 2) + ks];
    acc = __builtin_amdgcn_mfma_f32_16x16x32_f16(af, bh8, acc, 0, 0, 0);
    acc = __builtin_amdgcn_mfma_f32_16x16x32_f16(af, bl8, acc, 0, 0, 0);
  }

  // full row-sum of p: reduce over the 4 k-slot groups
  psum += __shfl_xor(psum, 16);
  psum += __shfl_xor(psum, 32);
  if (l < 16) s_ps[w][col] = psum;   // lane col holds row col's psum
  __syncthreads();

  const int b = bh >> 2, h = bh & 3;
  const float bc = bias[col];
#pragma unroll
  for (int r = 0; r < 4; ++r) {
    const int row = ks * 4 + r;                 // C/D row = query row in tile
    const float inv = 1.f / s_ps[w][row];
    float v = fmaf(acc[r], inv, bc);
    v = v > 0.f ? v : exp2f(v * LOG2E) - 1.f;   // elu
    x1[((size_t)(b * Nn + i0 + row)) * FH + h * F1n + col] = v;
  }
}

// ---------------------------------------------------------------------------
// Stats2: mean/rstd per (b, c) of x1 [16,1024,64] -> stats [b][2][64]
// ---------------------------------------------------------------------------
__global__ __launch_bounds__(1024) void k_stats2(
    const float* __restrict__ x1, float* __restrict__ stats)
{
  const int b = blockIdx.x;
  const int t = threadIdx.x;
  const int c = t & 63, seg = t >> 6;

  __shared__ float s_sum[16][65];
  __shared__ float s_ssq[16][65];

  const float* xb = x1 + (size_t)b * Nn * FH;
  float sum = 0.f, ssq = 0.f;
#pragma unroll 4
  for (int k = 0; k < 64; k++) {
    float v = xb[(seg * 64 + k) * FH + c];
    sum += v; ssq += v * v;
  }
  s_sum[seg][c] = sum; s_ssq[seg][c] = ssq;
  __syncthreads();
  if (t < 64) {
    float s = 0.f, q = 0.f;
#pragma unroll
    for (int k = 0; k < 16; k++) { s += s_sum[k][t]; q += s_ssq[k][t]; }
    const float mean = s * (1.f / Nn);
    const float var  = fmaf(-mean, mean, q * (1.f / Nn));
    stats[b * 128 + t]      = mean;
    stats[b * 128 + 64 + t] = rsqrtf(var + EPS);
  }
}

// ---------------------------------------------------------------------------
// Proj2: normalize + project -> hpT2 hi/lo fp16 [b][32ch][1024n], src2/dst2
// grid = 16 b * 16 tiles(64 rows), block = 256 (r = t&63, og = t>>6)
// ---------------------------------------------------------------------------
__global__ __launch_bounds__(256, 4) void k_proj2(
    const float* __restrict__ x1, const float* __restrict__ stats,
    const float* __restrict__ w2,
    const float* __restrict__ asrc, const float* __restrict__ adst,
    short* __restrict__ hpT_hi, short* __restrict__ hpT_lo,
    float* __restrict__ src, float* __restrict__ dst)
{
  const int b    = blockIdx.x >> 4;
  const int tile = blockIdx.x & 15;
  const int t    = threadIdx.x;
  const int r    = t & 63, og = t >> 6;

  __shared__ float s_x[64 * 65];          // padded rows
  __shared__ float s_wt[F2n * FH];        // [o][f]
  __shared__ float s_mean[64], s_rstd[64];
  __shared__ float s_as[F2n], s_ad[F2n];
  __shared__ float s_sd[4][64][2];

  const float* xb = x1 + (size_t)b * Nn * FH + (size_t)tile * 64 * FH;
  for (int idx = t; idx < 64 * FH; idx += 256) {
    const int rr = idx >> 6, f = idx & 63;
    s_x[rr * 65 + f] = xb[idx];
  }
  for (int idx = t; idx < F2n * FH; idx += 256) {
    const int f = idx & 63, o = idx >> 6;
    s_wt[idx] = w2[f * F2n + o];
  }
  if (t < 64)                 s_mean[t] = stats[b * 128 + t];
  else if (t < 128)           s_rstd[t - 64] = stats[b * 128 + t];
  if (t < F2n) { s_as[t] = asrc[t]; s_ad[t] = adst[t]; }
  __syncthreads();
  for (int idx = t; idx < 64 * FH; idx += 256) {
    const int rr = idx >> 6, f = idx & 63;
    s_x[rr * 65 + f] = (s_x[rr * 65 + f] - s_mean[f]) * s_rstd[f];
  }
  __syncthreads();

  const int n    = tile * 64 + r;
  const int base = b * Nn + n;
  float sdot = 0.f, ddot = 0.f;
#pragma unroll 1
  for (int oo = 0; oo < 8; oo++) {
    const int o = og * 8 + oo;
    float acc = 0.f;
#pragma unroll
    for (int f = 0; f < FH; f++)
      acc = fmaf(s_x[r * 65 + f], s_wt[o * FH + f], acc);
    sdot = fmaf(acc, s_as[o], sdot);
    ddot = fmaf(acc, s_ad[o], ddot);
    const _Float16 hh = (_Float16)acc;
    const _Float16 hl = (_Float16)(acc - (float)hh);
    const size_t idx = ((size_t)b * F2n + o) * Nn + n;
    hpT_hi[idx] = __builtin_bit_cast(short, hh);
    hpT_lo[idx] = __builtin_bit_cast(short, hl);
  }

  s_sd[og][r][0] = sdot; s_sd[og][r][1] = ddot;
  __syncthreads();
  if (og == 0) {
    float s = 0.f, d = 0.f;
#pragma unroll
    for (int g = 0; g < 4; g++) { s += s_sd[g][r][0]; d += s_sd[g][r][1]; }
    src[base] = s;
    dst[base] = d;
  }
}

// ---------------------------------------------------------------------------
// Attn2 (fp16 MFMA PV, V hi+lo) + bias -> out [b,n,32]
// grid = 16 b * 64 tiles(16 rows) = 1024 blocks, block 256 = 4 waves.
// Wave jq owns j in [jq*256,(jq+1)*256); LDS combine across waves.
// ---------------------------------------------------------------------------
__global__ __launch_bounds__(256) void k_attn2(
    const short* __restrict__ hpT_hi, const short* __restrict__ hpT_lo,
    const float* __restrict__ src, const float* __restrict__ dst,
    const float* __restrict__ bias, float* __restrict__ out)
{
  const int b    = blockIdx.x >> 6;
  const int tile = blockIdx.x & 63;
  const int t    = threadIdx.x;
  const int jq   = t >> 6;      // wave = j-quarter
  const int l    = t & 63;
  const int col  = l & 15;
  const int ks   = l >> 4;

  __shared__ float s_dst[Nn];
  __shared__ float s_red[4];
  __shared__ float s_comb[3][64][9];
  __shared__ float s_ps[16];

  const float* dp = dst + b * Nn;
  float lm = -1e30f;
  for (int j = t; j < Nn; j += 256) { float v = dp[j]; s_dst[j] = v; lm = fmaxf(lm, v); }
#pragma unroll
  for (int mask = 32; mask >= 1; mask >>= 1) lm = fmaxf(lm, __shfl_xor(lm, mask));
  if (l == 0) s_red[jq] = lm;
  __syncthreads();
  const float dmax = fmaxf(fmaxf(s_red[0], s_red[1]), fmaxf(s_red[2], s_red[3]));

  const int i0 = tile * 16;
  const float si = src[b * Nn + i0 + col];
  const float t0v = si + dmax;
  const float em  = fmaxf(t0v, ALPHA * t0v) * LOG2E;

  auto pexp = [&](float dv) {
    const float tt = si + dv;
    const float u  = fmaxf(tt, ALPHA * tt);
    return exp2f(fmaf(u, LOG2E, -em));
  };

  const half8* bph = reinterpret_cast<const half8*>(hpT_hi + (size_t)b * F2n * Nn);
  const half8* bpl = reinterpret_cast<const half8*>(hpT_lo + (size_t)b * F2n * Nn);
  f32x4 acc0 = {0.f, 0.f, 0.f, 0.f};
  f32x4 acc1 = {0.f, 0.f, 0.f, 0.f};
  float psum = 0.f;

#pragma unroll 2
  for (int kb = 0; kb < 8; ++kb) {
    const int jb = jq * 8 + kb;
    const int jo = (jb << 5) | (ks << 3);
    const float4 dA = *reinterpret_cast<const float4*>(&s_dst[jo]);
    const float4 dB = *reinterpret_cast<const float4*>(&s_dst[jo + 4]);
    half8 af;
    const _Float16 q0 = (_Float16)pexp(dA.x); af[0] = q0;
    const _Float16 q1 = (_Float16)pexp(dA.y); af[1] = q1;
    const _Float16 q2 = (_Float16)pexp(dA.z); af[2] = q2;
    const _Float16 q3 = (_Float16)pexp(dA.w); af[3] = q3;
    const _Float16 q4 = (_Float16)pexp(dB.x); af[4] = q4;
    const _Float16 q5 = (_Float16)pexp(dB.y); af[5] = q5;
    const _Float16 q6 = (_Float16)pexp(dB.z); af[6] = q6;
    const _Float16 q7 = (_Float16)pexp(dB.w); af[7] = q7;
    psum += (((float)q0 + (float)q1) + ((float)q2 + (float)q3)) +
            (((float)q4 + (float)q5) + ((float)q6 + (float)q7));

    const half8 bh0 = bph[col * 128 + (jb << 2) + ks];
    const half8 bl0 = bpl[col * 128 + (jb << 2) + ks];
    const half8 bh1 = bph[(col + 16) * 128 + (jb << 2) + ks];
    const half8 bl1 = bpl[(col + 16) * 128 + (jb << 2) + ks];
    acc0 = __builtin_amdgcn_mfma_f32_16x16x32_f16(af, bh0, acc0, 0, 0, 0);
    acc0 = __builtin_amdgcn_mfma_f32_16x16x32_f16(af, bl0, acc0, 0, 0, 0);
    acc1 = __builtin_amdgcn_mfma_f32_16x16x32_f16(af, bh1, acc1, 0, 0, 0);
    acc1 = __builtin_amdgcn_mfma_f32_16x16x32_f16(af, bl1, acc1, 0, 0, 0);
  }

  if (jq > 0) {
#pragma unroll
    for (int r = 0; r < 4; ++r) {
      s_comb[jq - 1][l][r]     = acc0[r];
      s_comb[jq - 1][l][r + 4] = acc1[r];
    }
    s_comb[jq - 1][l][8] = psum;
  }
  __syncthreads();

  if (jq == 0) {
#pragma unroll
    for (int g = 0; g < 3; ++g) {
#pragma unroll
      for (int r = 0; r < 4; ++r) {
        acc0[r] += s_comb[g][l][r];
        acc1[r] += s_comb[g][l][r + 4];
      }
      psum += s_comb[g][l][8];
    }
    psum += __shfl_xor(psum, 16);
    psum += __shfl_xor(psum, 32);
    if (l < 16) s_ps[col] = psum;    // same-wave LDS: ordered, no barrier needed

    const float bc0 = bias[col];
    const float bc1 = bias[col + 16];
#pragma unroll
    for (int r = 0; r < 4; ++r) {
      const int row = ks * 4 + r;
      const float inv = 1.f / s_ps[row];
      float* op = out + ((size_t)(b * Nn + i0 + row)) * F2n;
      op[col]      = fmaf(acc0[r], inv, bc0);
      op[col + 16] = fmaf(acc1[r], inv, bc1);
    }
  }
}

extern "C" void kernel_launch(void* const* d_in, const int* in_sizes, int n_in,
                              void* d_out, int out_size, void* d_ws, size_t ws_size,
                              hipStream_t stream) {
  (void)in_sizes; (void)n_in; (void)out_size; (void)ws_size;
  const float* x   = (const float*)d_in[0];
  const float* w1  = (const float*)d_in[1];
  const float* as1 = (const float*)d_in[2];
  const float* ad1 = (const float*)d_in[3];
  const float* b1  = (const float*)d_in[4];
  const float* w2  = (const float*)d_in[5];
  const float* as2 = (const float*)d_in[6];
  const float* ad2 = (const float*)d_in[7];
  const float* b2  = (const float*)d_in[8];
  float* out = (float*)d_out;

  float* ws = (float*)d_ws;
  // fp16 arrays sized in f32-equivalents (2 shorts per float)
  short* hpT1_hi = (short*)ws;                         // 64*16*1024 = 1,048,576 sh = 524288 f
  short* hpT1_lo = (short*)(ws + 524288);              // 524288 f
  short* hpT2_hi = (short*)(ws + 1048576);             // 16*32*1024 = 524,288 sh = 262144 f
  short* hpT2_lo = (short*)(ws + 1048576 + 262144);    // 262144 f
  float* x1      = ws + 1048576 + 524288;              // 16*1024*64 = 1,048,576 f
  float* src1    = x1 + 1048576;                       // 65536
  float* dst1    = src1 + 65536;                       // 65536
  float* src2    = dst1 + 65536;                       // 16384
  float* dst2    = src2 + 16384;                       // 16384
  float* stats1  = dst2 + 16384;                       // 1024
  float* stats2  = stats1 + 1024;                      // 2048
  // total ~2.79M floats = 11.2 MB of workspace

  k_stats1<<<16, 1024, 0, stream>>>(x, stats1);
  k_proj1<<<256, 256, 0, stream>>>(x, stats1, w1, as1, ad1, hpT1_hi, hpT1_lo, src1, dst1);
  k_attn1<<<1024, 256, 0, stream>>>(hpT1_hi, hpT1_lo, src1, dst1, b1, x1);
  k_stats2<<<16, 1024, 0, stream>>>(x1, stats2);
  k_proj2<<<256, 256, 0, stream>>>(x1, stats2, w2, as2, ad2, hpT2_hi, hpT2_lo, src2, dst2);
  k_attn2<<<1024, 256, 0, stream>>>(hpT2_hi, hpT2_lo, src2, dst2, b2, out);
}

// Round 7
// 142.343 us; speedup vs baseline: 4.5850x; 1.0733x over previous
//
#include <hip/hip_runtime.h>

// ProxemicsFieldGenerator: 2-layer GAT on dense graph.
// b=16, n=1024, f0=32, h0=4, f1=16, FH=64, f2=32, h1=1.
// 4-kernel pipeline:
//  K1 proj1: per-block redundant instnorm stats (L2-cached) + projection ->
//            hpT1 hi/lo fp16 + src1/dst1; also zeroes the layer-2 stats accum.
//  K2 attn1: fp16-MFMA PV + bias + elu -> x1; atomically accumulates layer-2
//            per-channel (sum, ssq) into statsAcc.
//  K3 proj2: finalizes stats from statsAcc (128 floats) + projection.
//  K4 attn2: fp16-MFMA PV + bias -> out.

namespace {
constexpr int Nn  = 1024;
constexpr int F0  = 32;
constexpr int F1n = 16;
constexpr int FH  = 64;   // h0 * f1
constexpr int F2n = 32;
constexpr float LOG2E = 1.4426950408889634f;
constexpr float EPS   = 1e-5f;
constexpr float ALPHA = 0.2f;
}

typedef __attribute__((ext_vector_type(8))) _Float16 half8;
typedef __attribute__((ext_vector_type(4))) float f32x4;

// ---------------------------------------------------------------------------
// K1 proj1: grid = 16 b * 16 tiles(64 rows), block = 256 (r = t&63, h = t>>6)
// ---------------------------------------------------------------------------
__global__ __launch_bounds__(256) void k_proj1(
    const float* __restrict__ x, const float* __restrict__ w1,
    const float* __restrict__ asrc, const float* __restrict__ adst,
    short* __restrict__ hpT_hi, short* __restrict__ hpT_lo,
    float* __restrict__ src, float* __restrict__ dst,
    float* __restrict__ statsAcc)
{
  const int b    = blockIdx.x >> 4;
  const int tile = blockIdx.x & 15;
  const int t    = threadIdx.x;
  const int r    = t & 63, h = t >> 6;

  __shared__ float  s_sum[8][33];
  __shared__ float  s_ssq[8][33];
  __shared__ float  s_mean[32], s_rstd[32];
  __shared__ float4 s_wt4[4 * F1n * (F0 / 4)];   // [h][o][f/4]
  __shared__ float  s_as[64], s_ad[64];

  // zero the layer-2 stats accumulator (ws is poisoned each call)
  if (tile == 0 && t < 128) statsAcc[b * 128 + t] = 0.f;

  // --- weights / attention vectors to LDS ---
  float* s_wt = reinterpret_cast<float*>(s_wt4);
  for (int idx = t; idx < 4 * F1n * F0; idx += 256) {
    const int f = idx & 31, ho = idx >> 5;
    s_wt[idx] = w1[((ho >> 4) * F0 + f) * F1n + (ho & 15)];
  }
  if (t < 64) { s_as[t] = asrc[t]; s_ad[t] = adst[t]; }

  // --- redundant per-block stats over all 1024 rows (x is L2/L3-resident) ---
  const float* xb = x + (size_t)b * Nn * F0;
  {
    const int c = t & 31, seg = t >> 5;
    float sum = 0.f, ssq = 0.f;
#pragma unroll 8
    for (int nn = seg; nn < Nn; nn += 8) {
      float v = xb[nn * F0 + c];
      sum += v; ssq += v * v;
    }
    s_sum[seg][c] = sum; s_ssq[seg][c] = ssq;
  }
  __syncthreads();
  if (t < 32) {
    float s = 0.f, q = 0.f;
#pragma unroll
    for (int k = 0; k < 8; k++) { s += s_sum[k][t]; q += s_ssq[k][t]; }
    const float mean = s * (1.f / Nn);
    const float var  = fmaf(-mean, mean, q * (1.f / Nn));
    s_mean[t] = mean;
    s_rstd[t] = rsqrtf(var + EPS);
  }
  __syncthreads();

  // --- one row per thread, x in registers ---
  const int n  = tile * 64 + r;
  const int bh = b * 4 + h;
  float4 xr[F0 / 4];
  const float4* xrow = reinterpret_cast<const float4*>(xb + (size_t)n * F0);
#pragma unroll
  for (int k = 0; k < F0 / 4; k++) {
    float4 v = xrow[k];
    v.x = (v.x - s_mean[k * 4 + 0]) * s_rstd[k * 4 + 0];
    v.y = (v.y - s_mean[k * 4 + 1]) * s_rstd[k * 4 + 1];
    v.z = (v.z - s_mean[k * 4 + 2]) * s_rstd[k * 4 + 2];
    v.w = (v.w - s_mean[k * 4 + 3]) * s_rstd[k * 4 + 3];
    xr[k] = v;
  }

  float sdot = 0.f, ddot = 0.f;
#pragma unroll 1
  for (int o = 0; o < F1n; o++) {
    float acc = 0.f;
#pragma unroll
    for (int k = 0; k < F0 / 4; k++) {
      const float4 wv = s_wt4[(h * F1n + o) * (F0 / 4) + k];
      const float4 xv = xr[k];
      acc = fmaf(xv.x, wv.x, acc); acc = fmaf(xv.y, wv.y, acc);
      acc = fmaf(xv.z, wv.z, acc); acc = fmaf(xv.w, wv.w, acc);
    }
    sdot = fmaf(acc, s_as[h * F1n + o], sdot);
    ddot = fmaf(acc, s_ad[h * F1n + o], ddot);
    const _Float16 hh = (_Float16)acc;
    const _Float16 hl = (_Float16)(acc - (float)hh);
    const size_t idx = ((size_t)bh * F1n + o) * Nn + n;
    hpT_hi[idx] = __builtin_bit_cast(short, hh);
    hpT_lo[idx] = __builtin_bit_cast(short, hl);
  }
  src[bh * Nn + n] = sdot;
  dst[bh * Nn + n] = ddot;
}

// ---------------------------------------------------------------------------
// K2 attn1: fp16 MFMA PV (V hi+lo) + bias + elu -> x1; atomic layer-2 stats.
// grid = 64 bh * 16 tiles = 1024 blocks, block 256 = 4 waves x 16 rows.
// ---------------------------------------------------------------------------
__global__ __launch_bounds__(256) void k_attn1(
    const short* __restrict__ hpT_hi, const short* __restrict__ hpT_lo,
    const float* __restrict__ src, const float* __restrict__ dst,
    const float* __restrict__ bias, float* __restrict__ x1,
    float* __restrict__ statsAcc)
{
  const int bh   = blockIdx.x >> 4;
  const int tile = blockIdx.x & 15;
  const int t    = threadIdx.x;
  const int w    = t >> 6;
  const int l    = t & 63;
  const int col  = l & 15;      // A-row (= query row) and C/D col (= channel)
  const int ks   = l >> 4;      // k-slot 0..3

  __shared__ float s_dst[Nn];
  __shared__ float s_red[4];
  __shared__ float s_ps[4][16];

  const float* dp = dst + bh * Nn;
  float lm = -1e30f;
  for (int j = t; j < Nn; j += 256) { float v = dp[j]; s_dst[j] = v; lm = fmaxf(lm, v); }
#pragma unroll
  for (int mask = 32; mask >= 1; mask >>= 1) lm = fmaxf(lm, __shfl_xor(lm, mask));
  if (l == 0) s_red[w] = lm;
  __syncthreads();
  const float dmax = fmaxf(fmaxf(s_red[0], s_red[1]), fmaxf(s_red[2], s_red[3]));

  const int i0 = tile * 64 + w * 16;
  const float si = src[bh * Nn + i0 + col];
  const float t0v = si + dmax;
  const float em  = fmaxf(t0v, ALPHA * t0v) * LOG2E;   // lrelu monotone => row max

  auto pexp = [&](float dv) {
    const float tt = si + dv;
    const float u  = fmaxf(tt, ALPHA * tt);
    return exp2f(fmaf(u, LOG2E, -em));
  };

  const half8* bph = reinterpret_cast<const half8*>(hpT_hi + (size_t)bh * F1n * Nn);
  const half8* bpl = reinterpret_cast<const half8*>(hpT_lo + (size_t)bh * F1n * Nn);
  f32x4 acc = {0.f, 0.f, 0.f, 0.f};
  float psum = 0.f;

#pragma unroll 2
  for (int jb = 0; jb < 32; ++jb) {
    const int jo = (jb << 5) | (ks << 3);
    const float4 dA = *reinterpret_cast<const float4*>(&s_dst[jo]);
    const float4 dB = *reinterpret_cast<const float4*>(&s_dst[jo + 4]);
    half8 af;
    const _Float16 q0 = (_Float16)pexp(dA.x); af[0] = q0;
    const _Float16 q1 = (_Float16)pexp(dA.y); af[1] = q1;
    const _Float16 q2 = (_Float16)pexp(dA.z); af[2] = q2;
    const _Float16 q3 = (_Float16)pexp(dA.w); af[3] = q3;
    const _Float16 q4 = (_Float16)pexp(dB.x); af[4] = q4;
    const _Float16 q5 = (_Float16)pexp(dB.y); af[5] = q5;
    const _Float16 q6 = (_Float16)pexp(dB.z); af[6] = q6;
    const _Float16 q7 = (_Float16)pexp(dB.w); af[7] = q7;
    psum += (((float)q0 + (float)q1) + ((float)q2 + (float)q3)) +
            (((float)q4 + (float)q5) + ((float)q6 + (float)q7));

    const half8 bh8 = bph[col * 128 + (jb << 2) + ks];
    const half8 bl8 = bpl[col * 128 + (jb << 2) + ks];
    acc = __builtin_amdgcn_mfma_f32_16x16x32_f16(af, bh8, acc, 0, 0, 0);
    acc = __builtin_amdgcn_mfma_f32_16x16x32_f16(af, bl8, acc, 0, 0, 0);
  }

  psum += __shfl_xor(psum, 16);
  psum += __shfl_xor(psum, 32);
  if (l < 16) s_ps[w][col] = psum;
  __syncthreads();

  const int b = bh >> 2, h = bh & 3;
  const float bc = bias[col];
  float sv = 0.f, sq = 0.f;
#pragma unroll
  for (int r = 0; r < 4; ++r) {
    const int row = ks * 4 + r;
    const float inv = 1.f / s_ps[w][row];
    float v = fmaf(acc[r], inv, bc);
    v = v > 0.f ? v : exp2f(v * LOG2E) - 1.f;   // elu
    x1[((size_t)(b * Nn + i0 + row)) * FH + h * F1n + col] = v;
    sv += v; sq += v * v;
  }
  // layer-2 instnorm partial stats: reduce over ks groups -> 16-row sums/col
  sv += __shfl_xor(sv, 16); sq += __shfl_xor(sq, 16);
  sv += __shfl_xor(sv, 32); sq += __shfl_xor(sq, 32);
  if (l < 16) {
    const int ch = h * F1n + col;
    atomicAdd(&statsAcc[b * 128 + ch], sv);
    atomicAdd(&statsAcc[b * 128 + 64 + ch], sq);
  }
}

// ---------------------------------------------------------------------------
// K3 proj2: grid = 16 b * 16 tiles(64 rows), block = 256 (r = t&63, og = t>>6)
// Stats from statsAcc (accumulated by attn1). x1 row in registers.
// ---------------------------------------------------------------------------
__global__ __launch_bounds__(256) void k_proj2(
    const float* __restrict__ x1, const float* __restrict__ statsAcc,
    const float* __restrict__ w2,
    const float* __restrict__ asrc, const float* __restrict__ adst,
    short* __restrict__ hpT_hi, short* __restrict__ hpT_lo,
    float* __restrict__ src, float* __restrict__ dst)
{
  const int b    = blockIdx.x >> 4;
  const int tile = blockIdx.x & 15;
  const int t    = threadIdx.x;
  const int r    = t & 63, og = t >> 6;

  __shared__ float  s_mean[64], s_rstd[64];
  __shared__ float4 s_wt4[F2n * (FH / 4)];   // [o][f/4]
  __shared__ float  s_as[F2n], s_ad[F2n];
  __shared__ float  s_sd[4][64][2];

  float* s_wt = reinterpret_cast<float*>(s_wt4);
  for (int idx = t; idx < F2n * FH; idx += 256) {
    const int f = idx & 63, o = idx >> 6;
    s_wt[idx] = w2[f * F2n + o];
  }
  if (t < F2n) { s_as[t] = asrc[t]; s_ad[t] = adst[t]; }
  if (t < 64) {
    const float s = statsAcc[b * 128 + t];
    const float q = statsAcc[b * 128 + 64 + t];
    const float mean = s * (1.f / Nn);
    const float var  = fmaf(-mean, mean, q * (1.f / Nn));
    s_mean[t] = mean;
    s_rstd[t] = rsqrtf(var + EPS);
  }
  __syncthreads();

  const int n    = tile * 64 + r;
  const int base = b * Nn + n;
  float4 xr[FH / 4];
  const float4* xrow = reinterpret_cast<const float4*>(
      x1 + (size_t)b * Nn * FH + (size_t)n * FH);
#pragma unroll
  for (int k = 0; k < FH / 4; k++) {
    float4 v = xrow[k];
    v.x = (v.x - s_mean[k * 4 + 0]) * s_rstd[k * 4 + 0];
    v.y = (v.y - s_mean[k * 4 + 1]) * s_rstd[k * 4 + 1];
    v.z = (v.z - s_mean[k * 4 + 2]) * s_rstd[k * 4 + 2];
    v.w = (v.w - s_mean[k * 4 + 3]) * s_rstd[k * 4 + 3];
    xr[k] = v;
  }

  float sdot = 0.f, ddot = 0.f;
#pragma unroll 1
  for (int oo = 0; oo < 8; oo++) {
    const int o = og * 8 + oo;
    float acc = 0.f;
#pragma unroll
    for (int k = 0; k < FH / 4; k++) {
      const float4 wv = s_wt4[o * (FH / 4) + k];
      const float4 xv = xr[k];
      acc = fmaf(xv.x, wv.x, acc); acc = fmaf(xv.y, wv.y, acc);
      acc = fmaf(xv.z, wv.z, acc); acc = fmaf(xv.w, wv.w, acc);
    }
    sdot = fmaf(acc, s_as[o], sdot);
    ddot = fmaf(acc, s_ad[o], ddot);
    const _Float16 hh = (_Float16)acc;
    const _Float16 hl = (_Float16)(acc - (float)hh);
    const size_t idx = ((size_t)b * F2n + o) * Nn + n;
    hpT_hi[idx] = __builtin_bit_cast(short, hh);
    hpT_lo[idx] = __builtin_bit_cast(short, hl);
  }

  s_sd[og][r][0] = sdot; s_sd[og][r][1] = ddot;
  __syncthreads();
  if (og == 0) {
    float s = 0.f, d = 0.f;
#pragma unroll
    for (int g = 0; g < 4; g++) { s += s_sd[g][r][0]; d += s_sd[g][r][1]; }
    src[base] = s;
    dst[base] = d;
  }
}

// ---------------------------------------------------------------------------
// K4 attn2: fp16 MFMA PV (V hi+lo) + bias -> out [b,n,32]
// grid = 16 b * 64 tiles(16 rows) = 1024 blocks, block 256 = 4 waves.
// ---------------------------------------------------------------------------
__global__ __launch_bounds__(256) void k_attn2(
    const short* __restrict__ hpT_hi, const short* __restrict__ hpT_lo,
    const float* __restrict__ src, const float* __restrict__ dst,
    const float* __restrict__ bias, float* __restrict__ out)
{
  const int b    = blockIdx.x >> 6;
  const int tile = blockIdx.x & 63;
  const int t    = threadIdx.x;
  const int jq   = t >> 6;      // wave = j-quarter
  const int l    = t & 63;
  const int col  = l & 15;
  const int ks   = l >> 4;

  __shared__ float s_dst[Nn];
  __shared__ float s_red[4];
  __shared__ float s_comb[3][64][9];
  __shared__ float s_ps[16];

  const float* dp = dst + b * Nn;
  float lm = -1e30f;
  for (int j = t; j < Nn; j += 256) { float v = dp[j]; s_dst[j] = v; lm = fmaxf(lm, v); }
#pragma unroll
  for (int mask = 32; mask >= 1; mask >>= 1) lm = fmaxf(lm, __shfl_xor(lm, mask));
  if (l == 0) s_red[jq] = lm;
  __syncthreads();
  const float dmax = fmaxf(fmaxf(s_red[0], s_red[1]), fmaxf(s_red[2], s_red[3]));

  const int i0 = tile * 16;
  const float si = src[b * Nn + i0 + col];
  const float t0v = si + dmax;
  const float em  = fmaxf(t0v, ALPHA * t0v) * LOG2E;

  auto pexp = [&](float dv) {
    const float tt = si + dv;
    const float u  = fmaxf(tt, ALPHA * tt);
    return exp2f(fmaf(u, LOG2E, -em));
  };

  const half8* bph = reinterpret_cast<const half8*>(hpT_hi + (size_t)b * F2n * Nn);
  const half8* bpl = reinterpret_cast<const half8*>(hpT_lo + (size_t)b * F2n * Nn);
  f32x4 acc0 = {0.f, 0.f, 0.f, 0.f};
  f32x4 acc1 = {0.f, 0.f, 0.f, 0.f};
  float psum = 0.f;

#pragma unroll 2
  for (int kb = 0; kb < 8; ++kb) {
    const int jb = jq * 8 + kb;
    const int jo = (jb << 5) | (ks << 3);
    const float4 dA = *reinterpret_cast<const float4*>(&s_dst[jo]);
    const float4 dB = *reinterpret_cast<const float4*>(&s_dst[jo + 4]);
    half8 af;
    const _Float16 q0 = (_Float16)pexp(dA.x); af[0] = q0;
    const _Float16 q1 = (_Float16)pexp(dA.y); af[1] = q1;
    const _Float16 q2 = (_Float16)pexp(dA.z); af[2] = q2;
    const _Float16 q3 = (_Float16)pexp(dA.w); af[3] = q3;
    const _Float16 q4 = (_Float16)pexp(dB.x); af[4] = q4;
    const _Float16 q5 = (_Float16)pexp(dB.y); af[5] = q5;
    const _Float16 q6 = (_Float16)pexp(dB.z); af[6] = q6;
    const _Float16 q7 = (_Float16)pexp(dB.w); af[7] = q7;
    psum += (((float)q0 + (float)q1) + ((float)q2 + (float)q3)) +
            (((float)q4 + (float)q5) + ((float)q6 + (float)q7));

    const half8 bh0 = bph[col * 128 + (jb << 2) + ks];
    const half8 bl0 = bpl[col * 128 + (jb << 2) + ks];
    const half8 bh1 = bph[(col + 16) * 128 + (jb << 2) + ks];
    const half8 bl1 = bpl[(col + 16) * 128 + (jb << 2) + ks];
    acc0 = __builtin_amdgcn_mfma_f32_16x16x32_f16(af, bh0, acc0, 0, 0, 0);
    acc0 = __builtin_amdgcn_mfma_f32_16x16x32_f16(af, bl0, acc0, 0, 0, 0);
    acc1 = __builtin_amdgcn_mfma_f32_16x16x32_f16(af, bh1, acc1, 0, 0, 0);
    acc1 = __builtin_amdgcn_mfma_f32_16x16x32_f16(af, bl1, acc1, 0, 0, 0);
  }

  if (jq > 0) {
#pragma unroll
    for (int r = 0; r < 4; ++r) {
      s_comb[jq - 1][l][r]     = acc0[r];
      s_comb[jq - 1][l][r + 4] = acc1[r];
    }
    s_comb[jq - 1][l][8] = psum;
  }
  __syncthreads();

  if (jq == 0) {
#pragma unroll
    for (int g = 0; g < 3; ++g) {
#pragma unroll
      for (int r = 0; r < 4; ++r) {
        acc0[r] += s_comb[g][l][r];
        acc1[r] += s_comb[g][l][r + 4];
      }
      psum += s_comb[g][l][8];
    }
    psum += __shfl_xor(psum, 16);
    psum += __shfl_xor(psum, 32);
    if (l < 16) s_ps[col] = psum;    // same-wave LDS: ordered

    const float bc0 = bias[col];
    const float bc1 = bias[col + 16];
#pragma unroll
    for (int r = 0; r < 4; ++r) {
      const int row = ks * 4 + r;
      const float inv = 1.f / s_ps[row];
      float* op = out + ((size_t)(b * Nn + i0 + row)) * F2n;
      op[col]      = fmaf(acc0[r], inv, bc0);
      op[col + 16] = fmaf(acc1[r], inv, bc1);
    }
  }
}

extern "C" void kernel_launch(void* const* d_in, const int* in_sizes, int n_in,
                              void* d_out, int out_size, void* d_ws, size_t ws_size,
                              hipStream_t stream) {
  (void)in_sizes; (void)n_in; (void)out_size; (void)ws_size;
  const float* x   = (const float*)d_in[0];
  const float* w1  = (const float*)d_in[1];
  const float* as1 = (const float*)d_in[2];
  const float* ad1 = (const float*)d_in[3];
  const float* b1  = (const float*)d_in[4];
  const float* w2  = (const float*)d_in[5];
  const float* as2 = (const float*)d_in[6];
  const float* ad2 = (const float*)d_in[7];
  const float* b2  = (const float*)d_in[8];
  float* out = (float*)d_out;

  float* ws = (float*)d_ws;
  short* hpT1_hi = (short*)ws;                         // 64*16*1024 sh = 524288 f
  short* hpT1_lo = (short*)(ws + 524288);              // 524288 f
  short* hpT2_hi = (short*)(ws + 1048576);             // 16*32*1024 sh = 262144 f
  short* hpT2_lo = (short*)(ws + 1048576 + 262144);    // 262144 f
  float* x1      = ws + 1048576 + 524288;              // 1048576 f
  float* src1    = x1 + 1048576;                       // 65536
  float* dst1    = src1 + 65536;                       // 65536
  float* src2    = dst1 + 65536;                       // 16384
  float* dst2    = src2 + 16384;                       // 16384
  float* statsA  = dst2 + 16384;                       // 16*128 = 2048

  k_proj1<<<256, 256, 0, stream>>>(x, w1, as1, ad1, hpT1_hi, hpT1_lo, src1, dst1, statsA);
  k_attn1<<<1024, 256, 0, stream>>>(hpT1_hi, hpT1_lo, src1, dst1, b1, x1, statsA);
  k_proj2<<<256, 256, 0, stream>>>(x1, statsA, w2, as2, ad2, hpT2_hi, hpT2_lo, src2, dst2);
  k_attn2<<<1024, 256, 0, stream>>>(hpT2_hi, hpT2_lo, src2, dst2, b2, out);
}